// Round 3
// baseline (1080.911 us; speedup 1.0000x reference)
//
#include <hip/hip_runtime.h>
#include <hip/hip_bf16.h>

#define S_ 577
#define B_ 16
#define H_ 16
#define DH 64
#define DM 1024
#define BH_ 256
#define DT_ 0.01f
#define BETA_ 4.0f
#define SCALE_ 0.125f
#define SPW 73      // s-rows per wave in k_ode
#define S8P 584     // 8*SPW (padded S)

typedef float f32x4 __attribute__((ext_vector_type(4)));
typedef short s16x8 __attribute__((ext_vector_type(8)));

__device__ inline short f2bf(float x) {
    unsigned b = __builtin_bit_cast(unsigned, x);
    b += 0x7fffu + ((b >> 16) & 1u);
    return (short)(b >> 16);
}
__device__ inline float bf2f(short s) {
    unsigned u = ((unsigned)(unsigned short)s) << 16;
    return __builtin_bit_cast(float, u);
}

// ---------------------------------------------------------------------------
// K1: per-(b,h) projections -> bf16 q,k,v ; omega ; z0 = (cos,sin)
// ---------------------------------------------------------------------------
__global__ __launch_bounds__(512) void k_proj(
    const float* __restrict__ x,
    const float* __restrict__ Wq, const float* __restrict__ bq,
    const float* __restrict__ Wk, const float* __restrict__ bk,
    const float* __restrict__ Wv, const float* __restrict__ bv,
    const float* __restrict__ Wom, const float* __restrict__ bom,
    const float* __restrict__ Wth, const float* __restrict__ bth,
    short* __restrict__ qh, short* __restrict__ kh, short* __restrict__ vh,
    float* __restrict__ om, float* __restrict__ zp)
{
    __shared__ __align__(16) float Wq_l[4096], Wk_l[4096], Wv_l[4096];
    __shared__ float Wom_l[64], Wth_l[64];
    int bh = blockIdx.x, b = bh >> 4, h = bh & 15;
    int tid = threadIdx.x;
    for (int i = tid; i < 4096; i += 512) {
        Wq_l[i] = Wq[(size_t)h*4096 + i];
        Wk_l[i] = Wk[(size_t)h*4096 + i];
        Wv_l[i] = Wv[(size_t)h*4096 + i];
    }
    if (tid < 64) { Wom_l[tid] = Wom[h*64 + tid]; Wth_l[tid] = Wth[h*64 + tid]; }
    __syncthreads();
    int wid = tid >> 6, lane = tid & 63;
    float bqv = bq[h*64 + lane], bkv = bk[h*64 + lane], bvv = bv[h*64 + lane];
    float bomv = bom[h], bthv = bth[h];
    for (int sb = wid*4; sb < S_; sb += 32) {
        float xr[4]; bool ok[4];
        #pragma unroll
        for (int r = 0; r < 4; ++r) {
            int s = sb + r; ok[r] = (s < S_);
            float xv = 0.f;
            if (ok[r]) xv = x[(size_t)b*S_*DM + (size_t)s*DM + h*DH + lane];
            if (!isfinite(xv)) xv = 0.f;
            xr[r] = xv;
        }
        float qa[4] = {0,0,0,0}, ka[4] = {0,0,0,0}, va[4] = {0,0,0,0};
        #pragma unroll 8
        for (int d = 0; d < 64; ++d) {
            float wq = Wq_l[d*64 + lane], wk = Wk_l[d*64 + lane], wv = Wv_l[d*64 + lane];
            #pragma unroll
            for (int r = 0; r < 4; ++r) {
                float xd = __shfl(xr[r], d, 64);
                qa[r] = fmaf(xd, wq, qa[r]);
                ka[r] = fmaf(xd, wk, ka[r]);
                va[r] = fmaf(xd, wv, va[r]);
            }
        }
        #pragma unroll
        for (int r = 0; r < 4; ++r) {
            float omp = xr[r] * Wom_l[lane], thp = xr[r] * Wth_l[lane];
            #pragma unroll
            for (int m = 32; m; m >>= 1) {
                omp += __shfl_xor(omp, m, 64);
                thp += __shfl_xor(thp, m, 64);
            }
            if (ok[r]) {
                int s = sb + r;
                size_t base = (size_t)bh*S_*DH + (size_t)s*DH + lane;
                qh[base] = f2bf(qa[r] + bqv);
                kh[base] = f2bf(ka[r] + bkv);
                vh[base] = f2bf(va[r] + bvv);
                if (lane == 0) {
                    float oms = omp + bomv, th = thp + bthv;
                    om[(size_t)bh*S_ + s] = oms;
                    float si, co;
                    sincosf(th, &si, &co);
                    reinterpret_cast<float2*>(zp)[(size_t)bh*S_ + s] = make_float2(co, si);
                }
            }
        }
    }
}

// ---------------------------------------------------------------------------
// K2: Stuart-Landau ODE, register-resident. k: 37 packed-bf16 VGPRs (lane=e,
// s-pairs). q: 10 x s16x8 (phase-B row layout). LDS only z/z'/kz/omega
// (~16 KB) -> 2 blocks/CU. Zero in-loop global traffic.
// ---------------------------------------------------------------------------
__global__ __launch_bounds__(512, 4) void k_ode(
    const short* __restrict__ qh, const short* __restrict__ kh,
    const float* __restrict__ om,
    const float* __restrict__ mu, const float* __restrict__ kappa,
    const float* __restrict__ alpha, const int* __restrict__ nsim,
    float* __restrict__ zp)
{
    __shared__ float2 z_l[S8P], z1_l[S8P];
    __shared__ float2 kz_s[8][64];
    __shared__ float om_l[S8P];
    int bh = blockIdx.x, h = bh & 15;
    int tid = threadIdx.x, w = tid >> 6, lane = tid & 63;
    const short* kg = kh + (size_t)bh*S_*DH;
    const short* qg = qh + (size_t)bh*S_*DH;
    float2* zpg = reinterpret_cast<float2*>(zp) + (size_t)bh*S_;
    const float* omg = om + (size_t)bh*S_;
    for (int i = tid; i < S8P; i += 512) {
        float2 zv = (i < S_) ? zpg[i] : make_float2(0.f, 0.f);
        z_l[i] = zv; z1_l[i] = make_float2(0.f, 0.f);
        om_l[i] = (i < S_) ? omg[i] : 0.f;
    }
    int s0 = w * SPW;
    // --- k into registers: k_reg[j] = pack(k[s0+2j][lane], k[s0+2j+1][lane])
    unsigned k_reg[37];
    #pragma unroll
    for (int j = 0; j < 37; ++j) {
        int sA = s0 + 2*j, sB = sA + 1;
        unsigned lo = (sA < S_) ? (unsigned)(unsigned short)kg[(size_t)sA*DH + lane] : 0u;
        unsigned hi = (sB < S_ && 2*j + 1 < SPW) ? (unsigned)(unsigned short)kg[(size_t)sB*DH + lane] : 0u;
        k_reg[j] = lo | (hi << 16);
    }
    // --- q into registers: rows s0 + i8 + 8m, e-chunk d0..d0+7
    int i8 = lane >> 3, d0 = (lane & 7) << 3;
    s16x8 q_reg[10];
    #pragma unroll
    for (int m = 0; m < 10; ++m) {
        int li = i8 + 8*m, s = s0 + li;
        s16x8 v = {0,0,0,0,0,0,0,0};
        if (li < SPW && s < S_) v = *(const s16x8*)(qg + (size_t)s*DH + d0);
        q_reg[m] = v;
    }
    float ca = cosf(alpha[h]), sa = sinf(alpha[h]);
    float muv = mu[h];
    float cc = kappa[h] * SCALE_ / (float)S_;
    int NT = nsim[0];
    __syncthreads();

    for (int ev = 0; ev < 2*NT; ++ev) {
        bool second = ev & 1;
        const float2* zin = second ? z1_l : z_l;
        // phase A: partial kz[e=lane] over this wave's s-slice (k in regs)
        float ar0 = 0.f, ai0 = 0.f, ar1 = 0.f, ai1 = 0.f;
        #pragma unroll
        for (int j = 0; j < 37; ++j) {
            float2 z0 = zin[s0 + 2*j];
            float2 z1v = zin[s0 + 2*j + 1];
            float klo = __builtin_bit_cast(float, k_reg[j] << 16);
            float khi = __builtin_bit_cast(float, k_reg[j] & 0xffff0000u);
            ar0 = fmaf(klo, z0.x, ar0);  ai0 = fmaf(klo, z0.y, ai0);
            ar1 = fmaf(khi, z1v.x, ar1); ai1 = fmaf(khi, z1v.y, ai1);
        }
        kz_s[w][lane] = make_float2(ar0 + ar1, ai0 + ai1);
        __syncthreads();
        if (tid < 64) {
            float2 t = kz_s[0][lane];
            #pragma unroll
            for (int w2 = 1; w2 < 8; ++w2) { float2 u = kz_s[w2][lane]; t.x += u.x; t.y += u.y; }
            kz_s[0][lane] = t;
        }
        __syncthreads();
        float kzr[8], kzi[8];
        #pragma unroll
        for (int j = 0; j < 8; ++j) { float2 t = kz_s[0][d0 + j]; kzr[j] = t.x; kzi[j] = t.y; }
        // phase B: u_s = cc * q_s . kz (q in regs), Stuart-Landau + Heun
        #pragma unroll
        for (int m = 0; m < 10; ++m) {
            int li = i8 + 8*m, s = s0 + li;
            bool act = (li < SPW) && (s < S_);
            float ur = 0.f, ui = 0.f;
            #pragma unroll
            for (int j = 0; j < 8; ++j) {
                float qv = bf2f(q_reg[m][j]);
                ur = fmaf(qv, kzr[j], ur);
                ui = fmaf(qv, kzi[j], ui);
            }
            #pragma unroll
            for (int mm = 1; mm < 8; mm <<= 1) {
                ur += __shfl_xor(ur, mm, 64);
                ui += __shfl_xor(ui, mm, 64);
            }
            if (act && d0 == 0) {
                float2 z = zin[s];
                float omega_s = om_l[s];
                float urc = cc*ur, uic = cc*ui;
                float cr = ca*urc + sa*uic;
                float ci = ca*uic - sa*urc;
                float g = muv - (z.x*z.x + z.y*z.y);
                float dr = fmaf(g, z.x, fmaf(-omega_s, z.y, cr));
                float di = fmaf(g, z.y, fmaf( omega_s, z.x, ci));
                float2 zb = z_l[s];
                if (!second) {
                    z1_l[s] = make_float2(fmaf(DT_, dr, z.x), fmaf(DT_, di, z.y));
                    z_l[s]  = make_float2(fmaf(0.5f*DT_, dr, zb.x), fmaf(0.5f*DT_, di, zb.y));
                } else {
                    z_l[s]  = make_float2(fmaf(0.5f*DT_, dr, zb.x), fmaf(0.5f*DT_, di, zb.y));
                }
            }
        }
        __syncthreads();
    }
    for (int i = tid; i < S_; i += 512) zpg[i] = z_l[i];
}

// ---------------------------------------------------------------------------
// K3: dual flash attention, MFMA 16x16x32 bf16. (unchanged from round 2)
// ---------------------------------------------------------------------------
__global__ __launch_bounds__(512) void k_attn(
    const short* __restrict__ qh, const short* __restrict__ kh,
    const short* __restrict__ vh, const float* __restrict__ zp,
    const float* __restrict__ mix_logit, const float* __restrict__ band_logits,
    short* __restrict__ yh)
{
    __shared__ short q_l[128*64];
    __shared__ short k_l2[64*64];
    __shared__ short vT_l[64*64];
    __shared__ short P_l[8][2][1024];
    __shared__ float2 zs_l[128];
    __shared__ float2 zt_l[64];

    int blk = blockIdx.x;
    int bh = blk / 5, rc = blk - bh*5;
    int b = bh >> 4, h = bh & 15;
    int r0 = rc * 128;
    int tid = threadIdx.x, w = tid >> 6, lane = tid & 63;
    int c = lane & 15, g = lane >> 4;

    const short* qg = qh + (size_t)bh*S_*DH;
    const short* kg = kh + (size_t)bh*S_*DH;
    const short* vg = vh + (size_t)bh*S_*DH;
    const float2* zpg = (const float2*)zp + (size_t)bh*S_;

    #pragma unroll
    for (int i = 0; i < 2; ++i) {
        int cid = tid + 512*i;
        int row = cid >> 3, ch = cid & 7;
        int s = r0 + row;
        s16x8 val = {0,0,0,0,0,0,0,0};
        if (s < S_) val = *(const s16x8*)(qg + (size_t)s*DH + ch*8);
        *(s16x8*)&q_l[row*64 + ((ch*8) ^ ((row&7)<<3))] = val;
    }
    if (tid < 128) {
        float2 z = (r0 + tid < S_) ? zpg[r0 + tid] : make_float2(0.f,0.f);
        zs_l[tid] = make_float2(z.x*BETA_, z.y*BETA_);
    }
    __syncthreads();

    s16x8 qf0, qf1;
    {
        int row = w*16 + c;
        qf0 = *(const s16x8*)&q_l[row*64 + ((g*8)      ^ ((row&7)<<3))];
        qf1 = *(const s16x8*)&q_l[row*64 + ((g*8 + 32) ^ ((row&7)<<3))];
    }

    f32x4 accv[4], accr[4];
    float m_v[4], m_r[4], Z_v[4], Z_r[4];
    #pragma unroll
    for (int i = 0; i < 4; ++i) {
        accv[i] = (f32x4){0.f,0.f,0.f,0.f};
        accr[i] = (f32x4){0.f,0.f,0.f,0.f};
        m_v[i] = -1e30f; m_r[i] = -1e30f; Z_v[i] = 0.f; Z_r[i] = 0.f;
    }

    for (int tt = 0; tt < 10; ++tt) {
        int t0g = tt * 64;
        __syncthreads();
        {
            int row = tid >> 3, ch = tid & 7;
            int t = t0g + row;
            s16x8 val = {0,0,0,0,0,0,0,0};
            if (t < S_) val = *(const s16x8*)(kg + (size_t)t*DH + ch*8);
            *(s16x8*)&k_l2[row*64 + ((ch*8) ^ ((row&7)<<3))] = val;
        }
        {
            int t = tid >> 3, d0 = (tid & 7) << 3;
            s16x8 vv = {0,0,0,0,0,0,0,0};
            if (t0g + t < S_) vv = *(const s16x8*)(vg + (size_t)(t0g+t)*DH + d0);
            #pragma unroll
            for (int j = 0; j < 8; ++j)
                vT_l[(d0+j)*64 + (t ^ (((d0+j)&7)<<3))] = vv[j];
        }
        if (tid < 64) zt_l[tid] = (t0g + tid < S_) ? zpg[t0g + tid] : make_float2(0.f,0.f);
        __syncthreads();

        f32x4 sv[4];
        #pragma unroll
        for (int sub = 0; sub < 4; ++sub) {
            int row = sub*16 + c;
            s16x8 kf0 = *(const s16x8*)&k_l2[row*64 + ((g*8)      ^ ((c&7)<<3))];
            s16x8 kf1 = *(const s16x8*)&k_l2[row*64 + ((g*8 + 32) ^ ((c&7)<<3))];
            f32x4 a = {0.f,0.f,0.f,0.f};
            a = __builtin_amdgcn_mfma_f32_16x16x32_bf16(qf0, kf0, a, 0, 0, 0);
            a = __builtin_amdgcn_mfma_f32_16x16x32_bf16(qf1, kf1, a, 0, 0, 0);
            sv[sub] = a * SCALE_;
        }
        float2 zt_s[4];
        #pragma unroll
        for (int sub = 0; sub < 4; ++sub) zt_s[sub] = zt_l[sub*16 + c];

        bool mask = (t0g + 63 >= S_);
        #pragma unroll
        for (int r = 0; r < 4; ++r) {
            int srow = w*16 + (g<<2) + r;
            float2 zs = zs_l[srow];
            float sv_r[4], sr_r[4];
            #pragma unroll
            for (int sub = 0; sub < 4; ++sub) {
                float a = sv[sub][r];
                float rr = fmaf(zs.x, zt_s[sub].x, zs.y * zt_s[sub].y);
                bool bad = mask && ((t0g + sub*16 + c) >= S_);
                sv_r[sub] = bad ? -1e30f : a;
                sr_r[sub] = bad ? -1e30f : rr;
            }
            float mlv = fmaxf(fmaxf(sv_r[0],sv_r[1]), fmaxf(sv_r[2],sv_r[3]));
            float mlr = fmaxf(fmaxf(sr_r[0],sr_r[1]), fmaxf(sr_r[2],sr_r[3]));
            #pragma unroll
            for (int mm = 1; mm < 16; mm <<= 1) {
                mlv = fmaxf(mlv, __shfl_xor(mlv, mm, 64));
                mlr = fmaxf(mlr, __shfl_xor(mlr, mm, 64));
            }
            float nmv = fmaxf(m_v[r], mlv), nmr = fmaxf(m_r[r], mlr);
            float fv = __expf(m_v[r] - nmv), fr = __expf(m_r[r] - nmr);
            m_v[r] = nmv; m_r[r] = nmr;
            int sl = (g<<2) + r;
            float sumv = 0.f, sumr = 0.f;
            #pragma unroll
            for (int sub = 0; sub < 4; ++sub) {
                float pv = __expf(sv_r[sub] - nmv);
                float pr = __expf(sr_r[sub] - nmr);
                sumv += pv; sumr += pr;
                int t = sub*16 + c;
                P_l[w][0][sl*64 + (t ^ ((sl&7)<<3))] = f2bf(pv);
                P_l[w][1][sl*64 + (t ^ ((sl&7)<<3))] = f2bf(pr);
            }
            #pragma unroll
            for (int mm = 1; mm < 16; mm <<= 1) {
                sumv += __shfl_xor(sumv, mm, 64);
                sumr += __shfl_xor(sumr, mm, 64);
            }
            Z_v[r] = fmaf(Z_v[r], fv, sumv);
            Z_r[r] = fmaf(Z_r[r], fr, sumr);
            #pragma unroll
            for (int d = 0; d < 4; ++d) { accv[d][r] *= fv; accr[d][r] *= fr; }
        }

        #pragma unroll
        for (int hh = 0; hh < 2; ++hh) {
            int kc = g*8 + 32*hh;
            s16x8 pa_v = *(const s16x8*)&P_l[w][0][c*64 + (kc ^ ((c&7)<<3))];
            s16x8 pa_r = *(const s16x8*)&P_l[w][1][c*64 + (kc ^ ((c&7)<<3))];
            #pragma unroll
            for (int d = 0; d < 4; ++d) {
                int row = d*16 + c;
                s16x8 vf = *(const s16x8*)&vT_l[row*64 + (kc ^ ((c&7)<<3))];
                accv[d] = __builtin_amdgcn_mfma_f32_16x16x32_bf16(pa_v, vf, accv[d], 0, 0, 0);
                accr[d] = __builtin_amdgcn_mfma_f32_16x16x32_bf16(pa_r, vf, accr[d], 0, 0, 0);
            }
        }
    }

    float mixv = 1.f/(1.f + __expf(-mix_logit[h]));
    #pragma unroll
    for (int d = 0; d < 4; ++d) {
        float gate = 1.f/(1.f + __expf(-band_logits[h*4 + d]));
        #pragma unroll
        for (int r = 0; r < 4; ++r) {
            int s = r0 + w*16 + (g<<2) + r;
            if (s < S_) {
                float val = mixv*gate*(accr[d][r]/Z_r[r]) + (1.f-mixv)*(accv[d][r]/Z_v[r]);
                yh[(size_t)b*S_*DM + (size_t)s*DM + h*DH + d*16 + c] = f2bf(val);
            }
        }
    }
}

// ---------------------------------------------------------------------------
// K4b: Wo (f32 [k][n]) -> WoT (bf16 [n][k]) tile transpose
// ---------------------------------------------------------------------------
__global__ __launch_bounds__(256) void k_cvt(
    const float* __restrict__ Wo, short* __restrict__ Bt)
{
    __shared__ short tl[64][65];
    int k0 = blockIdx.x * 64, n0 = blockIdx.y * 64;
    int tid = threadIdx.x;
    int r = tid >> 2, cb = (tid & 3) * 16;
    #pragma unroll
    for (int j4 = 0; j4 < 4; ++j4) {
        float4 v = *reinterpret_cast<const float4*>(Wo + (size_t)(k0+r)*1024 + n0 + cb + j4*4);
        tl[r][cb + j4*4 + 0] = f2bf(v.x);
        tl[r][cb + j4*4 + 1] = f2bf(v.y);
        tl[r][cb + j4*4 + 2] = f2bf(v.z);
        tl[r][cb + j4*4 + 3] = f2bf(v.w);
    }
    __syncthreads();
    s16x8 v0, v1;
    #pragma unroll
    for (int j = 0; j < 8; ++j) { v0[j] = tl[cb+j][r]; v1[j] = tl[cb+8+j][r]; }
    *(s16x8*)(Bt + (size_t)(n0+r)*1024 + k0 + cb)     = v0;
    *(s16x8*)(Bt + (size_t)(n0+r)*1024 + k0 + cb + 8) = v1;
}

// ---------------------------------------------------------------------------
// K4: out = y(9232x1024 bf16) @ Wo + bo, MFMA 16x16x32 bf16, 128x128 tile.
// ---------------------------------------------------------------------------
__global__ __launch_bounds__(256) void k_gemm(
    const short* __restrict__ A, const short* __restrict__ Bt,
    const float* __restrict__ bias, float* __restrict__ out)
{
    const int M = B_ * S_;
    __shared__ short A_l[128*64];
    __shared__ short B_l[128*64];
    int m0 = blockIdx.x * 128, n0 = blockIdx.y * 128;
    int tid = threadIdx.x, w = tid >> 6, lane = tid & 63;
    int c = lane & 15, g = lane >> 4;
    int mb = (w & 1) * 64, nb = (w >> 1) * 64;
    f32x4 acc[4][4];
    #pragma unroll
    for (int i = 0; i < 4; ++i)
        #pragma unroll
        for (int j = 0; j < 4; ++j) acc[i][j] = (f32x4){0.f,0.f,0.f,0.f};
    for (int k0 = 0; k0 < 1024; k0 += 64) {
        __syncthreads();
        #pragma unroll
        for (int i = 0; i < 4; ++i) {
            int cid = tid + 256*i;
            int row = cid >> 3, ch = cid & 7;
            int m = m0 + row;
            s16x8 av = {0,0,0,0,0,0,0,0};
            if (m < M) av = *(const s16x8*)(A + (size_t)m*1024 + k0 + ch*8);
            *(s16x8*)&A_l[row*64 + ((ch*8) ^ ((row&7)<<3))] = av;
            s16x8 bv = *(const s16x8*)(Bt + (size_t)(n0+row)*1024 + k0 + ch*8);
            *(s16x8*)&B_l[row*64 + ((ch*8) ^ ((row&7)<<3))] = bv;
        }
        __syncthreads();
        s16x8 af[4][2], bf[4][2];
        #pragma unroll
        for (int i = 0; i < 4; ++i) {
            int ra = mb + i*16 + c;
            af[i][0] = *(const s16x8*)&A_l[ra*64 + ((g*8)      ^ ((c&7)<<3))];
            af[i][1] = *(const s16x8*)&A_l[ra*64 + ((g*8 + 32) ^ ((c&7)<<3))];
            int rb = nb + i*16 + c;
            bf[i][0] = *(const s16x8*)&B_l[rb*64 + ((g*8)      ^ ((c&7)<<3))];
            bf[i][1] = *(const s16x8*)&B_l[rb*64 + ((g*8 + 32) ^ ((c&7)<<3))];
        }
        #pragma unroll
        for (int i = 0; i < 4; ++i)
            #pragma unroll
            for (int j = 0; j < 4; ++j) {
                acc[i][j] = __builtin_amdgcn_mfma_f32_16x16x32_bf16(af[i][0], bf[j][0], acc[i][j], 0, 0, 0);
                acc[i][j] = __builtin_amdgcn_mfma_f32_16x16x32_bf16(af[i][1], bf[j][1], acc[i][j], 0, 0, 0);
            }
    }
    #pragma unroll
    for (int j = 0; j < 4; ++j) {
        float bv = bias[n0 + nb + j*16 + c];
        #pragma unroll
        for (int i = 0; i < 4; ++i)
            #pragma unroll
            for (int r = 0; r < 4; ++r) {
                int m = m0 + mb + i*16 + 4*g + r;
                if (m < M) out[(size_t)m*1024 + n0 + nb + j*16 + c] = acc[i][j][r] + bv;
            }
    }
}

// ---------------------------------------------------------------------------
extern "C" void kernel_launch(void* const* d_in, const int* in_sizes, int n_in,
                              void* d_out, int out_size, void* d_ws, size_t ws_size,
                              hipStream_t stream)
{
    const float* x   = (const float*)d_in[0];
    const float* Wq  = (const float*)d_in[1];
    const float* bq  = (const float*)d_in[2];
    const float* Wk  = (const float*)d_in[3];
    const float* bk  = (const float*)d_in[4];
    const float* Wv  = (const float*)d_in[5];
    const float* bv  = (const float*)d_in[6];
    const float* Wom = (const float*)d_in[7];
    const float* bom = (const float*)d_in[8];
    const float* Wth = (const float*)d_in[9];
    const float* bth = (const float*)d_in[10];
    const float* mu  = (const float*)d_in[11];
    const float* kap = (const float*)d_in[12];
    const float* alp = (const float*)d_in[13];
    const float* mix = (const float*)d_in[14];
    const float* bl  = (const float*)d_in[15];
    const float* Wo  = (const float*)d_in[16];
    const float* bo  = (const float*)d_in[17];
    const int* nsim  = (const int*)d_in[18];

    float* ws = (float*)d_ws;
    const size_t QKV = (size_t)BH_ * S_ * DH;    // 9,453,568
    float* qf = ws;                               // slot A (aliased below)
    float* kf = qf + QKV;                         // slot B (aliased below)
    float* om = kf + QKV;                         // BH*S
    float* zp = om + (size_t)BH_*S_;              // 2*BH*S
    short* qh = (short*)(zp + (size_t)2*BH_*S_);  // bf16 q
    short* kh = qh + QKV;                         // bf16 k
    short* vh = kh + QKV;                         // bf16 v
    short* yh  = (short*)qf;                      // bf16 y (attn out)
    short* WoT = (short*)kf;                      // bf16 Wo^T
    float* outf = (float*)d_out;

    k_proj<<<BH_, 512, 0, stream>>>(x, Wq, bq, Wk, bk, Wv, bv, Wom, bom, Wth, bth,
                                    qh, kh, vh, om, zp);
    k_ode<<<BH_, 512, 0, stream>>>(qh, kh, om, mu, kap, alp, nsim, zp);
    k_cvt<<<dim3(16,16), 256, 0, stream>>>(Wo, WoT);
    k_attn<<<BH_*5, 512, 0, stream>>>(qh, kh, vh, zp, mix, bl, yh);
    dim3 gg(73, 8);
    k_gemm<<<gg, 256, 0, stream>>>(yh, WoT, bo, outf);
}

// Round 4
// 552.288 us; speedup vs baseline: 1.9572x; 1.9572x over previous
//
#include <hip/hip_runtime.h>
#include <hip/hip_bf16.h>

#define S_ 577
#define B_ 16
#define H_ 16
#define DH 64
#define DM 1024
#define BH_ 256
#define DT_ 0.01f
#define BETA_ 4.0f
#define SCALE_ 0.125f
#define SPW 73      // s-rows per wave (phase B ownership)
#define SPP 292     // s-pairs (584/2) summed in phase A
#define KPR 293     // kp row stride in u32 (293 % 32 = 5, odd -> conflict-free)

typedef float f32x4 __attribute__((ext_vector_type(4)));
typedef short s16x8 __attribute__((ext_vector_type(8)));

__device__ inline short f2bf(float x) {
    unsigned b = __builtin_bit_cast(unsigned, x);
    b += 0x7fffu + ((b >> 16) & 1u);
    return (short)(b >> 16);
}
__device__ inline float bf2f(short s) {
    unsigned u = ((unsigned)(unsigned short)s) << 16;
    return __builtin_bit_cast(float, u);
}

// ---------------------------------------------------------------------------
// K1: per-(b,h) projections -> bf16 q,k,v ; omega ; z0 = (cos,sin)
// ---------------------------------------------------------------------------
__global__ __launch_bounds__(512) void k_proj(
    const float* __restrict__ x,
    const float* __restrict__ Wq, const float* __restrict__ bq,
    const float* __restrict__ Wk, const float* __restrict__ bk,
    const float* __restrict__ Wv, const float* __restrict__ bv,
    const float* __restrict__ Wom, const float* __restrict__ bom,
    const float* __restrict__ Wth, const float* __restrict__ bth,
    short* __restrict__ qh, short* __restrict__ kh, short* __restrict__ vh,
    float* __restrict__ om, float* __restrict__ zp)
{
    __shared__ __align__(16) float Wq_l[4096], Wk_l[4096], Wv_l[4096];
    __shared__ float Wom_l[64], Wth_l[64];
    int bh = blockIdx.x, b = bh >> 4, h = bh & 15;
    int tid = threadIdx.x;
    for (int i = tid; i < 4096; i += 512) {
        Wq_l[i] = Wq[(size_t)h*4096 + i];
        Wk_l[i] = Wk[(size_t)h*4096 + i];
        Wv_l[i] = Wv[(size_t)h*4096 + i];
    }
    if (tid < 64) { Wom_l[tid] = Wom[h*64 + tid]; Wth_l[tid] = Wth[h*64 + tid]; }
    __syncthreads();
    int wid = tid >> 6, lane = tid & 63;
    float bqv = bq[h*64 + lane], bkv = bk[h*64 + lane], bvv = bv[h*64 + lane];
    float bomv = bom[h], bthv = bth[h];
    for (int sb = wid*4; sb < S_; sb += 32) {
        float xr[4]; bool ok[4];
        #pragma unroll
        for (int r = 0; r < 4; ++r) {
            int s = sb + r; ok[r] = (s < S_);
            float xv = 0.f;
            if (ok[r]) xv = x[(size_t)b*S_*DM + (size_t)s*DM + h*DH + lane];
            if (!isfinite(xv)) xv = 0.f;
            xr[r] = xv;
        }
        float qa[4] = {0,0,0,0}, ka[4] = {0,0,0,0}, va[4] = {0,0,0,0};
        #pragma unroll 8
        for (int d = 0; d < 64; ++d) {
            float wq = Wq_l[d*64 + lane], wk = Wk_l[d*64 + lane], wv = Wv_l[d*64 + lane];
            #pragma unroll
            for (int r = 0; r < 4; ++r) {
                float xd = __shfl(xr[r], d, 64);
                qa[r] = fmaf(xd, wq, qa[r]);
                ka[r] = fmaf(xd, wk, ka[r]);
                va[r] = fmaf(xd, wv, va[r]);
            }
        }
        #pragma unroll
        for (int r = 0; r < 4; ++r) {
            float omp = xr[r] * Wom_l[lane], thp = xr[r] * Wth_l[lane];
            #pragma unroll
            for (int m = 32; m; m >>= 1) {
                omp += __shfl_xor(omp, m, 64);
                thp += __shfl_xor(thp, m, 64);
            }
            if (ok[r]) {
                int s = sb + r;
                size_t base = (size_t)bh*S_*DH + (size_t)s*DH + lane;
                qh[base] = f2bf(qa[r] + bqv);
                kh[base] = f2bf(ka[r] + bkv);
                vh[base] = f2bf(va[r] + bvv);
                if (lane == 0) {
                    float oms = omp + bomv, th = thp + bthv;
                    om[(size_t)bh*S_ + s] = oms;
                    float si, co;
                    sincosf(th, &si, &co);
                    reinterpret_cast<float2*>(zp)[(size_t)bh*S_ + s] = make_float2(co, si);
                }
            }
        }
    }
}

// ---------------------------------------------------------------------------
// K2: Stuart-Landau ODE. k,q LDS-resident as bf16 (162.3 KB total LDS):
// k packed u32 s-pairs [e][sp] stride 293 (conflict-free), q XOR-swizzled
// [s][64]. Zero in-loop global traffic; 2 barriers/eval; omega in regs.
// ---------------------------------------------------------------------------
__global__ __launch_bounds__(512) void k_ode(
    const short* __restrict__ qh, const short* __restrict__ kh,
    const float* __restrict__ om,
    const float* __restrict__ mu, const float* __restrict__ kappa,
    const float* __restrict__ alpha, const int* __restrict__ nsim,
    float* __restrict__ zp)
{
    __shared__ __align__(16) unsigned kp_l[64*KPR];   // 75,008 B
    __shared__ __align__(16) short    q_l[S_*64];     // 73,856 B
    __shared__ __align__(16) float2   z_l[584];       // 4,672 B
    __shared__ __align__(16) float2   z1_l[584];      // 4,672 B
    __shared__ __align__(16) float2   kz_s[8][64];    // 4,096 B

    int bh = blockIdx.x, h = bh & 15;
    int tid = threadIdx.x, w = tid >> 6, lane = tid & 63;
    const short* kg = kh + (size_t)bh*S_*DH;
    const short* qg = qh + (size_t)bh*S_*DH;
    float2* zpg = reinterpret_cast<float2*>(zp) + (size_t)bh*S_;
    const float* omg = om + (size_t)bh*S_;

    // init z / z1 (padded rows zero)
    for (int i = tid; i < 584; i += 512) {
        z_l[i] = (i < S_) ? zpg[i] : make_float2(0.f, 0.f);
        z1_l[i] = make_float2(0.f, 0.f);
    }
    // stage k packed: kp[e][sp] = k[2sp][e] | (k[2sp+1][e] << 16)
    {
        int e0 = (tid & 7) * 8;
        for (int sp = tid >> 3; sp < SPP; sp += 64) {
            int sA = 2*sp, sB = 2*sp + 1;
            s16x8 ka = {0,0,0,0,0,0,0,0}, kb = ka;
            if (sA < S_) ka = *(const s16x8*)(kg + (size_t)sA*DH + e0);
            if (sB < S_) kb = *(const s16x8*)(kg + (size_t)sB*DH + e0);
            #pragma unroll
            for (int j = 0; j < 8; ++j)
                kp_l[(e0+j)*KPR + sp] =
                    ((unsigned)(unsigned short)ka[j]) |
                    (((unsigned)(unsigned short)kb[j]) << 16);
        }
    }
    // stage q swizzled: chunk (s,c) at q_l[s*64 + ((c*8) ^ ((s&7)<<3))]
    for (int cid = tid; cid < S_*8; cid += 512) {
        int s = cid >> 3, c = cid & 7;
        s16x8 v = *(const s16x8*)(qg + (size_t)s*DH + c*8);
        *(s16x8*)&q_l[s*64 + ((c*8) ^ ((s&7)<<3))] = v;
    }
    int i8 = lane >> 3, d0 = (lane & 7) << 3;
    int s0 = w * SPW;
    // omega for this lane's owned rows (only d0==0 lanes use it)
    float om_r[10];
    #pragma unroll
    for (int m2 = 0; m2 < 10; ++m2) {
        int li = i8 + 8*m2, s = s0 + li;
        om_r[m2] = (li < SPW && s < S_) ? omg[s] : 0.f;
    }
    float ca = cosf(alpha[h]), sa = sinf(alpha[h]);
    float muv = mu[h];
    float cc = kappa[h] * SCALE_ / (float)S_;
    int NT = nsim[0];
    int sp0 = w * 37, spE = min(SPP, sp0 + 37);
    __syncthreads();

    for (int ev = 0; ev < 2*NT; ++ev) {
        bool second = ev & 1;
        const float2* zin = second ? z1_l : z_l;
        // phase A: partial kz[e=lane] over this wave's sp-slice
        float ar = 0.f, ai = 0.f, br = 0.f, bi = 0.f;
        for (int sp = sp0; sp < spE; ++sp) {
            unsigned kv = kp_l[lane*KPR + sp];
            float4 zz = *reinterpret_cast<const float4*>(&zin[2*sp]); // z[2sp], z[2sp+1]
            float klo = __builtin_bit_cast(float, kv << 16);
            float khi = __builtin_bit_cast(float, kv & 0xffff0000u);
            ar = fmaf(klo, zz.x, ar); ai = fmaf(klo, zz.y, ai);
            br = fmaf(khi, zz.z, br); bi = fmaf(khi, zz.w, bi);
        }
        kz_s[w][lane] = make_float2(ar + br, ai + bi);
        __syncthreads();
        // all-wave replicated reduce: lane gets kz[e=lane]
        float sr = 0.f, si = 0.f;
        #pragma unroll
        for (int w2 = 0; w2 < 8; ++w2) {
            float2 t = kz_s[w2][lane];
            sr += t.x; si += t.y;
        }
        // redistribute: lane needs kz[d0..d0+7]
        float kzr[8], kzi[8];
        #pragma unroll
        for (int j = 0; j < 8; ++j) {
            kzr[j] = __shfl(sr, d0 + j, 64);
            kzi[j] = __shfl(si, d0 + j, 64);
        }
        // phase B: u_s = cc * q_s . kz ; Stuart-Landau + Heun
        #pragma unroll
        for (int m2 = 0; m2 < 10; ++m2) {
            int li = i8 + 8*m2, s = s0 + li;
            bool act = (li < SPW) && (s < S_);
            int sq = (s <= S_-1) ? s : S_-1;
            s16x8 qv = *(const s16x8*)&q_l[sq*64 + (d0 ^ ((sq&7)<<3))];
            float ur = 0.f, ui = 0.f;
            #pragma unroll
            for (int j = 0; j < 8; ++j) {
                float qf = bf2f(qv[j]);
                ur = fmaf(qf, kzr[j], ur);
                ui = fmaf(qf, kzi[j], ui);
            }
            #pragma unroll
            for (int mm = 1; mm < 8; mm <<= 1) {
                ur += __shfl_xor(ur, mm, 64);
                ui += __shfl_xor(ui, mm, 64);
            }
            if (act && d0 == 0) {
                float2 z = zin[s];
                float urc = cc*ur, uic = cc*ui;
                float cr = ca*urc + sa*uic;
                float ci = ca*uic - sa*urc;
                float g = muv - (z.x*z.x + z.y*z.y);
                float dr = fmaf(g, z.x, fmaf(-om_r[m2], z.y, cr));
                float di = fmaf(g, z.y, fmaf( om_r[m2], z.x, ci));
                float2 zb = z_l[s];
                if (!second) {
                    z1_l[s] = make_float2(fmaf(DT_, dr, z.x), fmaf(DT_, di, z.y));
                    z_l[s]  = make_float2(fmaf(0.5f*DT_, dr, zb.x), fmaf(0.5f*DT_, di, zb.y));
                } else {
                    z_l[s]  = make_float2(fmaf(0.5f*DT_, dr, zb.x), fmaf(0.5f*DT_, di, zb.y));
                }
            }
        }
        __syncthreads();
    }
    for (int i = tid; i < S_; i += 512) zpg[i] = z_l[i];
}

// ---------------------------------------------------------------------------
// K3: dual flash attention, MFMA 16x16x32 bf16. (unchanged, validated r2)
// ---------------------------------------------------------------------------
__global__ __launch_bounds__(512) void k_attn(
    const short* __restrict__ qh, const short* __restrict__ kh,
    const short* __restrict__ vh, const float* __restrict__ zp,
    const float* __restrict__ mix_logit, const float* __restrict__ band_logits,
    short* __restrict__ yh)
{
    __shared__ short q_l[128*64];
    __shared__ short k_l2[64*64];
    __shared__ short vT_l[64*64];
    __shared__ short P_l[8][2][1024];
    __shared__ float2 zs_l[128];
    __shared__ float2 zt_l[64];

    int blk = blockIdx.x;
    int bh = blk / 5, rc = blk - bh*5;
    int b = bh >> 4, h = bh & 15;
    int r0 = rc * 128;
    int tid = threadIdx.x, w = tid >> 6, lane = tid & 63;
    int c = lane & 15, g = lane >> 4;

    const short* qg = qh + (size_t)bh*S_*DH;
    const short* kg = kh + (size_t)bh*S_*DH;
    const short* vg = vh + (size_t)bh*S_*DH;
    const float2* zpg = (const float2*)zp + (size_t)bh*S_;

    #pragma unroll
    for (int i = 0; i < 2; ++i) {
        int cid = tid + 512*i;
        int row = cid >> 3, ch = cid & 7;
        int s = r0 + row;
        s16x8 val = {0,0,0,0,0,0,0,0};
        if (s < S_) val = *(const s16x8*)(qg + (size_t)s*DH + ch*8);
        *(s16x8*)&q_l[row*64 + ((ch*8) ^ ((row&7)<<3))] = val;
    }
    if (tid < 128) {
        float2 z = (r0 + tid < S_) ? zpg[r0 + tid] : make_float2(0.f,0.f);
        zs_l[tid] = make_float2(z.x*BETA_, z.y*BETA_);
    }
    __syncthreads();

    s16x8 qf0, qf1;
    {
        int row = w*16 + c;
        qf0 = *(const s16x8*)&q_l[row*64 + ((g*8)      ^ ((row&7)<<3))];
        qf1 = *(const s16x8*)&q_l[row*64 + ((g*8 + 32) ^ ((row&7)<<3))];
    }

    f32x4 accv[4], accr[4];
    float m_v[4], m_r[4], Z_v[4], Z_r[4];
    #pragma unroll
    for (int i = 0; i < 4; ++i) {
        accv[i] = (f32x4){0.f,0.f,0.f,0.f};
        accr[i] = (f32x4){0.f,0.f,0.f,0.f};
        m_v[i] = -1e30f; m_r[i] = -1e30f; Z_v[i] = 0.f; Z_r[i] = 0.f;
    }

    for (int tt = 0; tt < 10; ++tt) {
        int t0g = tt * 64;
        __syncthreads();
        {
            int row = tid >> 3, ch = tid & 7;
            int t = t0g + row;
            s16x8 val = {0,0,0,0,0,0,0,0};
            if (t < S_) val = *(const s16x8*)(kg + (size_t)t*DH + ch*8);
            *(s16x8*)&k_l2[row*64 + ((ch*8) ^ ((row&7)<<3))] = val;
        }
        {
            int t = tid >> 3, d0 = (tid & 7) << 3;
            s16x8 vv = {0,0,0,0,0,0,0,0};
            if (t0g + t < S_) vv = *(const s16x8*)(vg + (size_t)(t0g+t)*DH + d0);
            #pragma unroll
            for (int j = 0; j < 8; ++j)
                vT_l[(d0+j)*64 + (t ^ (((d0+j)&7)<<3))] = vv[j];
        }
        if (tid < 64) zt_l[tid] = (t0g + tid < S_) ? zpg[t0g + tid] : make_float2(0.f,0.f);
        __syncthreads();

        f32x4 sv[4];
        #pragma unroll
        for (int sub = 0; sub < 4; ++sub) {
            int row = sub*16 + c;
            s16x8 kf0 = *(const s16x8*)&k_l2[row*64 + ((g*8)      ^ ((c&7)<<3))];
            s16x8 kf1 = *(const s16x8*)&k_l2[row*64 + ((g*8 + 32) ^ ((c&7)<<3))];
            f32x4 a = {0.f,0.f,0.f,0.f};
            a = __builtin_amdgcn_mfma_f32_16x16x32_bf16(qf0, kf0, a, 0, 0, 0);
            a = __builtin_amdgcn_mfma_f32_16x16x32_bf16(qf1, kf1, a, 0, 0, 0);
            sv[sub] = a * SCALE_;
        }
        float2 zt_s[4];
        #pragma unroll
        for (int sub = 0; sub < 4; ++sub) zt_s[sub] = zt_l[sub*16 + c];

        bool mask = (t0g + 63 >= S_);
        #pragma unroll
        for (int r = 0; r < 4; ++r) {
            int srow = w*16 + (g<<2) + r;
            float2 zs = zs_l[srow];
            float sv_r[4], sr_r[4];
            #pragma unroll
            for (int sub = 0; sub < 4; ++sub) {
                float a = sv[sub][r];
                float rr = fmaf(zs.x, zt_s[sub].x, zs.y * zt_s[sub].y);
                bool bad = mask && ((t0g + sub*16 + c) >= S_);
                sv_r[sub] = bad ? -1e30f : a;
                sr_r[sub] = bad ? -1e30f : rr;
            }
            float mlv = fmaxf(fmaxf(sv_r[0],sv_r[1]), fmaxf(sv_r[2],sv_r[3]));
            float mlr = fmaxf(fmaxf(sr_r[0],sr_r[1]), fmaxf(sr_r[2],sr_r[3]));
            #pragma unroll
            for (int mm = 1; mm < 16; mm <<= 1) {
                mlv = fmaxf(mlv, __shfl_xor(mlv, mm, 64));
                mlr = fmaxf(mlr, __shfl_xor(mlr, mm, 64));
            }
            float nmv = fmaxf(m_v[r], mlv), nmr = fmaxf(m_r[r], mlr);
            float fv = __expf(m_v[r] - nmv), fr = __expf(m_r[r] - nmr);
            m_v[r] = nmv; m_r[r] = nmr;
            int sl = (g<<2) + r;
            float sumv = 0.f, sumr = 0.f;
            #pragma unroll
            for (int sub = 0; sub < 4; ++sub) {
                float pv = __expf(sv_r[sub] - nmv);
                float pr = __expf(sr_r[sub] - nmr);
                sumv += pv; sumr += pr;
                int t = sub*16 + c;
                P_l[w][0][sl*64 + (t ^ ((sl&7)<<3))] = f2bf(pv);
                P_l[w][1][sl*64 + (t ^ ((sl&7)<<3))] = f2bf(pr);
            }
            #pragma unroll
            for (int mm = 1; mm < 16; mm <<= 1) {
                sumv += __shfl_xor(sumv, mm, 64);
                sumr += __shfl_xor(sumr, mm, 64);
            }
            Z_v[r] = fmaf(Z_v[r], fv, sumv);
            Z_r[r] = fmaf(Z_r[r], fr, sumr);
            #pragma unroll
            for (int d = 0; d < 4; ++d) { accv[d][r] *= fv; accr[d][r] *= fr; }
        }

        #pragma unroll
        for (int hh = 0; hh < 2; ++hh) {
            int kc = g*8 + 32*hh;
            s16x8 pa_v = *(const s16x8*)&P_l[w][0][c*64 + (kc ^ ((c&7)<<3))];
            s16x8 pa_r = *(const s16x8*)&P_l[w][1][c*64 + (kc ^ ((c&7)<<3))];
            #pragma unroll
            for (int d = 0; d < 4; ++d) {
                int row = d*16 + c;
                s16x8 vf = *(const s16x8*)&vT_l[row*64 + (kc ^ ((c&7)<<3))];
                accv[d] = __builtin_amdgcn_mfma_f32_16x16x32_bf16(pa_v, vf, accv[d], 0, 0, 0);
                accr[d] = __builtin_amdgcn_mfma_f32_16x16x32_bf16(pa_r, vf, accr[d], 0, 0, 0);
            }
        }
    }

    float mixv = 1.f/(1.f + __expf(-mix_logit[h]));
    #pragma unroll
    for (int d = 0; d < 4; ++d) {
        float gate = 1.f/(1.f + __expf(-band_logits[h*4 + d]));
        #pragma unroll
        for (int r = 0; r < 4; ++r) {
            int s = r0 + w*16 + (g<<2) + r;
            if (s < S_) {
                float val = mixv*gate*(accr[d][r]/Z_r[r]) + (1.f-mixv)*(accv[d][r]/Z_v[r]);
                yh[(size_t)b*S_*DM + (size_t)s*DM + h*DH + d*16 + c] = f2bf(val);
            }
        }
    }
}

// ---------------------------------------------------------------------------
// K4b: Wo (f32 [k][n]) -> WoT (bf16 [n][k]) tile transpose
// ---------------------------------------------------------------------------
__global__ __launch_bounds__(256) void k_cvt(
    const float* __restrict__ Wo, short* __restrict__ Bt)
{
    __shared__ short tl[64][65];
    int k0 = blockIdx.x * 64, n0 = blockIdx.y * 64;
    int tid = threadIdx.x;
    int r = tid >> 2, cb = (tid & 3) * 16;
    #pragma unroll
    for (int j4 = 0; j4 < 4; ++j4) {
        float4 v = *reinterpret_cast<const float4*>(Wo + (size_t)(k0+r)*1024 + n0 + cb + j4*4);
        tl[r][cb + j4*4 + 0] = f2bf(v.x);
        tl[r][cb + j4*4 + 1] = f2bf(v.y);
        tl[r][cb + j4*4 + 2] = f2bf(v.z);
        tl[r][cb + j4*4 + 3] = f2bf(v.w);
    }
    __syncthreads();
    s16x8 v0, v1;
    #pragma unroll
    for (int j = 0; j < 8; ++j) { v0[j] = tl[cb+j][r]; v1[j] = tl[cb+8+j][r]; }
    *(s16x8*)(Bt + (size_t)(n0+r)*1024 + k0 + cb)     = v0;
    *(s16x8*)(Bt + (size_t)(n0+r)*1024 + k0 + cb + 8) = v1;
}

// ---------------------------------------------------------------------------
// K4: out = y(9232x1024 bf16) @ Wo + bo, MFMA 16x16x32 bf16, 128x128 tile.
// ---------------------------------------------------------------------------
__global__ __launch_bounds__(256) void k_gemm(
    const short* __restrict__ A, const short* __restrict__ Bt,
    const float* __restrict__ bias, float* __restrict__ out)
{
    const int M = B_ * S_;
    __shared__ short A_l[128*64];
    __shared__ short B_l[128*64];
    int m0 = blockIdx.x * 128, n0 = blockIdx.y * 128;
    int tid = threadIdx.x, w = tid >> 6, lane = tid & 63;
    int c = lane & 15, g = lane >> 4;
    int mb = (w & 1) * 64, nb = (w >> 1) * 64;
    f32x4 acc[4][4];
    #pragma unroll
    for (int i = 0; i < 4; ++i)
        #pragma unroll
        for (int j = 0; j < 4; ++j) acc[i][j] = (f32x4){0.f,0.f,0.f,0.f};
    for (int k0 = 0; k0 < 1024; k0 += 64) {
        __syncthreads();
        #pragma unroll
        for (int i = 0; i < 4; ++i) {
            int cid = tid + 256*i;
            int row = cid >> 3, ch = cid & 7;
            int m = m0 + row;
            s16x8 av = {0,0,0,0,0,0,0,0};
            if (m < M) av = *(const s16x8*)(A + (size_t)m*1024 + k0 + ch*8);
            *(s16x8*)&A_l[row*64 + ((ch*8) ^ ((row&7)<<3))] = av;
            s16x8 bv = *(const s16x8*)(Bt + (size_t)(n0+row)*1024 + k0 + ch*8);
            *(s16x8*)&B_l[row*64 + ((ch*8) ^ ((row&7)<<3))] = bv;
        }
        __syncthreads();
        s16x8 af[4][2], bf[4][2];
        #pragma unroll
        for (int i = 0; i < 4; ++i) {
            int ra = mb + i*16 + c;
            af[i][0] = *(const s16x8*)&A_l[ra*64 + ((g*8)      ^ ((c&7)<<3))];
            af[i][1] = *(const s16x8*)&A_l[ra*64 + ((g*8 + 32) ^ ((c&7)<<3))];
            int rb = nb + i*16 + c;
            bf[i][0] = *(const s16x8*)&B_l[rb*64 + ((g*8)      ^ ((c&7)<<3))];
            bf[i][1] = *(const s16x8*)&B_l[rb*64 + ((g*8 + 32) ^ ((c&7)<<3))];
        }
        #pragma unroll
        for (int i = 0; i < 4; ++i)
            #pragma unroll
            for (int j = 0; j < 4; ++j) {
                acc[i][j] = __builtin_amdgcn_mfma_f32_16x16x32_bf16(af[i][0], bf[j][0], acc[i][j], 0, 0, 0);
                acc[i][j] = __builtin_amdgcn_mfma_f32_16x16x32_bf16(af[i][1], bf[j][1], acc[i][j], 0, 0, 0);
            }
    }
    #pragma unroll
    for (int j = 0; j < 4; ++j) {
        float bv = bias[n0 + nb + j*16 + c];
        #pragma unroll
        for (int i = 0; i < 4; ++i)
            #pragma unroll
            for (int r = 0; r < 4; ++r) {
                int m = m0 + mb + i*16 + 4*g + r;
                if (m < M) out[(size_t)m*1024 + n0 + nb + j*16 + c] = acc[i][j][r] + bv;
            }
    }
}

// ---------------------------------------------------------------------------
extern "C" void kernel_launch(void* const* d_in, const int* in_sizes, int n_in,
                              void* d_out, int out_size, void* d_ws, size_t ws_size,
                              hipStream_t stream)
{
    const float* x   = (const float*)d_in[0];
    const float* Wq  = (const float*)d_in[1];
    const float* bq  = (const float*)d_in[2];
    const float* Wk  = (const float*)d_in[3];
    const float* bk  = (const float*)d_in[4];
    const float* Wv  = (const float*)d_in[5];
    const float* bv  = (const float*)d_in[6];
    const float* Wom = (const float*)d_in[7];
    const float* bom = (const float*)d_in[8];
    const float* Wth = (const float*)d_in[9];
    const float* bth = (const float*)d_in[10];
    const float* mu  = (const float*)d_in[11];
    const float* kap = (const float*)d_in[12];
    const float* alp = (const float*)d_in[13];
    const float* mix = (const float*)d_in[14];
    const float* bl  = (const float*)d_in[15];
    const float* Wo  = (const float*)d_in[16];
    const float* bo  = (const float*)d_in[17];
    const int* nsim  = (const int*)d_in[18];

    float* ws = (float*)d_ws;
    const size_t QKV = (size_t)BH_ * S_ * DH;    // 9,453,568
    float* qf = ws;                               // slot A (aliased below)
    float* kf = qf + QKV;                         // slot B (aliased below)
    float* om = kf + QKV;                         // BH*S
    float* zp = om + (size_t)BH_*S_;              // 2*BH*S
    short* qh = (short*)(zp + (size_t)2*BH_*S_);  // bf16 q
    short* kh = qh + QKV;                         // bf16 k
    short* vh = kh + QKV;                         // bf16 v
    short* yh  = (short*)qf;                      // bf16 y (attn out)
    short* WoT = (short*)kf;                      // bf16 Wo^T
    float* outf = (float*)d_out;

    k_proj<<<BH_, 512, 0, stream>>>(x, Wq, bq, Wk, bk, Wv, bv, Wom, bom, Wth, bth,
                                    qh, kh, vh, om, zp);
    k_ode<<<BH_, 512, 0, stream>>>(qh, kh, om, mu, kap, alp, nsim, zp);
    k_cvt<<<dim3(16,16), 256, 0, stream>>>(Wo, WoT);
    k_attn<<<BH_*5, 512, 0, stream>>>(qh, kh, vh, zp, mix, bl, yh);
    dim3 gg(73, 8);
    k_gemm<<<gg, 256, 0, stream>>>(yh, WoT, bo, outf);
}

// Round 7
// 417.185 us; speedup vs baseline: 2.5910x; 1.3238x over previous
//
#include <hip/hip_runtime.h>
#include <hip/hip_bf16.h>

#define S_ 577
#define B_ 16
#define H_ 16
#define DH 64
#define DM 1024
#define BH_ 256
#define DT_ 0.01f
#define BETA_ 4.0f
#define SCALE_ 0.125f
#define SPW 73      // s-rows per wave (k_ode phase B)
#define SPP 292     // s-pairs in k_ode phase A
#define KPR 293     // k_ode kp row stride (odd -> conflict-free)

typedef float f32x4 __attribute__((ext_vector_type(4)));
typedef short s16x8 __attribute__((ext_vector_type(8)));

__device__ inline short f2bf(float x) {
    unsigned b = __builtin_bit_cast(unsigned, x);
    b += 0x7fffu + ((b >> 16) & 1u);
    return (short)(b >> 16);
}
__device__ inline float bf2f(short s) {
    unsigned u = ((unsigned)(unsigned short)s) << 16;
    return __builtin_bit_cast(float, u);
}

// ---------------------------------------------------------------------------
// K1: per-(b,h) projections via MFMA (k_gemm-proven fragment pattern).
// W^T bf16 staged once per block; x staged bf16 per 128-row tile (nan_to_num).
// omega/theta kept full fp32 (8-lane shfl reduce during staging) -> z0.
// ---------------------------------------------------------------------------
__global__ __launch_bounds__(512) void k_proj(
    const float* __restrict__ x,
    const float* __restrict__ Wq, const float* __restrict__ bq,
    const float* __restrict__ Wk, const float* __restrict__ bk,
    const float* __restrict__ Wv, const float* __restrict__ bv,
    const float* __restrict__ Wom, const float* __restrict__ bom,
    const float* __restrict__ Wth, const float* __restrict__ bth,
    short* __restrict__ qh, short* __restrict__ kh, short* __restrict__ vh,
    float* __restrict__ om, float* __restrict__ zp)
{
    __shared__ __align__(16) short WqT[64*64], WkT[64*64], WvT[64*64]; // 24 KB
    __shared__ __align__(16) short X_l[128*64];                        // 16 KB
    __shared__ float Wom_l[64], Wth_l[64];

    int bh = blockIdx.x, b = bh >> 4, h = bh & 15;
    int tid = threadIdx.x, w = tid >> 6, lane = tid & 63;
    int c = lane & 15, g = lane >> 4;

    // ---- stage W^T (bf16, XOR-swizzled rows e): thread owns (d, e0..e0+7)
    {
        int d = tid >> 3, e0 = (tid & 7) << 3;
        const float* pq = Wq + (size_t)h*4096 + d*64 + e0;
        const float* pk = Wk + (size_t)h*4096 + d*64 + e0;
        const float* pv = Wv + (size_t)h*4096 + d*64 + e0;
        float4 q0 = *(const float4*)pq, q1 = *(const float4*)(pq + 4);
        float4 k0 = *(const float4*)pk, k1 = *(const float4*)(pk + 4);
        float4 v0 = *(const float4*)pv, v1 = *(const float4*)(pv + 4);
        float qv[8] = {q0.x,q0.y,q0.z,q0.w,q1.x,q1.y,q1.z,q1.w};
        float kv[8] = {k0.x,k0.y,k0.z,k0.w,k1.x,k1.y,k1.z,k1.w};
        float vv[8] = {v0.x,v0.y,v0.z,v0.w,v1.x,v1.y,v1.z,v1.w};
        #pragma unroll
        for (int j = 0; j < 8; ++j) {
            int e = e0 + j;
            int off = e*64 + (d ^ ((e&7)<<3));
            WqT[off] = f2bf(qv[j]);
            WkT[off] = f2bf(kv[j]);
            WvT[off] = f2bf(vv[j]);
        }
    }
    if (tid < 64) { Wom_l[tid] = Wom[h*64 + tid]; Wth_l[tid] = Wth[h*64 + tid]; }

    // per-lane biases (e = esub*16 + c)
    float bqv[4], bkv[4], bvv[4];
    #pragma unroll
    for (int e4 = 0; e4 < 4; ++e4) {
        bqv[e4] = bq[h*64 + e4*16 + c];
        bkv[e4] = bk[h*64 + e4*16 + c];
        bvv[e4] = bv[h*64 + e4*16 + c];
    }
    float bomv = bom[h], bthv = bth[h];

    const size_t xbase = (size_t)b*S_*DM + (size_t)h*DH;

    for (int t5 = 0; t5 < 5; ++t5) {
        int s0 = t5 * 128;
        __syncthreads();   // protect X_l from previous tile's fragment reads
        // ---- stage x tile bf16 swizzled + fp32 omega/theta
        #pragma unroll
        for (int i = 0; i < 2; ++i) {
            int cid = tid + 512*i;
            int row = cid >> 3, ch = cid & 7;
            int s = s0 + row;
            float xv[8];
            if (s < S_) {
                const float* px = x + xbase + (size_t)s*DM + ch*8;
                float4 a0 = *(const float4*)px, a1 = *(const float4*)(px + 4);
                xv[0]=a0.x; xv[1]=a0.y; xv[2]=a0.z; xv[3]=a0.w;
                xv[4]=a1.x; xv[5]=a1.y; xv[6]=a1.z; xv[7]=a1.w;
                #pragma unroll
                for (int j = 0; j < 8; ++j) if (!isfinite(xv[j])) xv[j] = 0.f;
            } else {
                #pragma unroll
                for (int j = 0; j < 8; ++j) xv[j] = 0.f;
            }
            s16x8 xb;
            #pragma unroll
            for (int j = 0; j < 8; ++j) xb[j] = f2bf(xv[j]);
            *(s16x8*)&X_l[row*64 + ((ch*8) ^ ((row&7)<<3))] = xb;
            float po = 0.f, pt = 0.f;
            #pragma unroll
            for (int j = 0; j < 8; ++j) {
                po = fmaf(xv[j], Wom_l[ch*8 + j], po);
                pt = fmaf(xv[j], Wth_l[ch*8 + j], pt);
            }
            po += __shfl_xor(po, 1, 64); pt += __shfl_xor(pt, 1, 64);
            po += __shfl_xor(po, 2, 64); pt += __shfl_xor(pt, 2, 64);
            po += __shfl_xor(po, 4, 64); pt += __shfl_xor(pt, 4, 64);
            if (ch == 0 && s < S_) {
                om[(size_t)bh*S_ + s] = po + bomv;
                float si, co;
                sincosf(pt + bthv, &si, &co);
                reinterpret_cast<float2*>(zp)[(size_t)bh*S_ + s] = make_float2(co, si);
            }
        }
        __syncthreads();
        // ---- MFMA: wave w computes rows s0 + w*16 + (0..15)
        int arow = w*16 + c;
        s16x8 xa0 = *(const s16x8*)&X_l[arow*64 + ((g*8)      ^ ((arow&7)<<3))];
        s16x8 xa1 = *(const s16x8*)&X_l[arow*64 + ((g*8 + 32) ^ ((arow&7)<<3))];

        const short* WT[3] = {WqT, WkT, WvT};
        short* dst[3] = {qh, kh, vh};
        #pragma unroll
        for (int o = 0; o < 3; ++o) {
            f32x4 acc[4];
            #pragma unroll
            for (int e4 = 0; e4 < 4; ++e4) {
                int brow = e4*16 + c;
                s16x8 b0 = *(const s16x8*)&WT[o][brow*64 + ((g*8)      ^ ((brow&7)<<3))];
                s16x8 b1 = *(const s16x8*)&WT[o][brow*64 + ((g*8 + 32) ^ ((brow&7)<<3))];
                f32x4 a = {0.f,0.f,0.f,0.f};
                a = __builtin_amdgcn_mfma_f32_16x16x32_bf16(xa0, b0, a, 0, 0, 0);
                a = __builtin_amdgcn_mfma_f32_16x16x32_bf16(xa1, b1, a, 0, 0, 0);
                acc[e4] = a;
            }
            float* bias = (o == 0) ? bqv : (o == 1) ? bkv : bvv;
            #pragma unroll
            for (int e4 = 0; e4 < 4; ++e4) {
                #pragma unroll
                for (int r = 0; r < 4; ++r) {
                    int s = s0 + w*16 + 4*g + r;
                    if (s < S_)
                        dst[o][(size_t)bh*S_*DH + (size_t)s*DH + e4*16 + c] =
                            f2bf(acc[e4][r] + bias[e4]);
                }
            }
        }
    }
}

// ---------------------------------------------------------------------------
// K2: Stuart-Landau ODE, LDS-resident bf16 k/q. (unchanged, validated r4)
// ---------------------------------------------------------------------------
__global__ __launch_bounds__(512) void k_ode(
    const short* __restrict__ qh, const short* __restrict__ kh,
    const float* __restrict__ om,
    const float* __restrict__ mu, const float* __restrict__ kappa,
    const float* __restrict__ alpha, const int* __restrict__ nsim,
    float* __restrict__ zp)
{
    __shared__ __align__(16) unsigned kp_l[64*KPR];
    __shared__ __align__(16) short    q_l[S_*64];
    __shared__ __align__(16) float2   z_l[584];
    __shared__ __align__(16) float2   z1_l[584];
    __shared__ __align__(16) float2   kz_s[8][64];

    int bh = blockIdx.x, h = bh & 15;
    int tid = threadIdx.x, w = tid >> 6, lane = tid & 63;
    const short* kg = kh + (size_t)bh*S_*DH;
    const short* qg = qh + (size_t)bh*S_*DH;
    float2* zpg = reinterpret_cast<float2*>(zp) + (size_t)bh*S_;
    const float* omg = om + (size_t)bh*S_;

    for (int i = tid; i < 584; i += 512) {
        z_l[i] = (i < S_) ? zpg[i] : make_float2(0.f, 0.f);
        z1_l[i] = make_float2(0.f, 0.f);
    }
    {
        int e0 = (tid & 7) * 8;
        for (int sp = tid >> 3; sp < SPP; sp += 64) {
            int sA = 2*sp, sB = 2*sp + 1;
            s16x8 ka = {0,0,0,0,0,0,0,0}, kb = ka;
            if (sA < S_) ka = *(const s16x8*)(kg + (size_t)sA*DH + e0);
            if (sB < S_) kb = *(const s16x8*)(kg + (size_t)sB*DH + e0);
            #pragma unroll
            for (int j = 0; j < 8; ++j)
                kp_l[(e0+j)*KPR + sp] =
                    ((unsigned)(unsigned short)ka[j]) |
                    (((unsigned)(unsigned short)kb[j]) << 16);
        }
    }
    for (int cid = tid; cid < S_*8; cid += 512) {
        int s = cid >> 3, c = cid & 7;
        s16x8 v = *(const s16x8*)(qg + (size_t)s*DH + c*8);
        *(s16x8*)&q_l[s*64 + ((c*8) ^ ((s&7)<<3))] = v;
    }
    int i8 = lane >> 3, d0 = (lane & 7) << 3;
    int s0 = w * SPW;
    float om_r[10];
    #pragma unroll
    for (int m2 = 0; m2 < 10; ++m2) {
        int li = i8 + 8*m2, s = s0 + li;
        om_r[m2] = (li < SPW && s < S_) ? omg[s] : 0.f;
    }
    float ca = cosf(alpha[h]), sa = sinf(alpha[h]);
    float muv = mu[h];
    float cc = kappa[h] * SCALE_ / (float)S_;
    int NT = nsim[0];
    int sp0 = w * 37, spE = min(SPP, sp0 + 37);
    __syncthreads();

    for (int ev = 0; ev < 2*NT; ++ev) {
        bool second = ev & 1;
        const float2* zin = second ? z1_l : z_l;
        float ar = 0.f, ai = 0.f, br = 0.f, bi = 0.f;
        for (int sp = sp0; sp < spE; ++sp) {
            unsigned kv = kp_l[lane*KPR + sp];
            float4 zz = *reinterpret_cast<const float4*>(&zin[2*sp]);
            float klo = __builtin_bit_cast(float, kv << 16);
            float khi = __builtin_bit_cast(float, kv & 0xffff0000u);
            ar = fmaf(klo, zz.x, ar); ai = fmaf(klo, zz.y, ai);
            br = fmaf(khi, zz.z, br); bi = fmaf(khi, zz.w, bi);
        }
        kz_s[w][lane] = make_float2(ar + br, ai + bi);
        __syncthreads();
        float sr = 0.f, si = 0.f;
        #pragma unroll
        for (int w2 = 0; w2 < 8; ++w2) {
            float2 t = kz_s[w2][lane];
            sr += t.x; si += t.y;
        }
        float kzr[8], kzi[8];
        #pragma unroll
        for (int j = 0; j < 8; ++j) {
            kzr[j] = __shfl(sr, d0 + j, 64);
            kzi[j] = __shfl(si, d0 + j, 64);
        }
        #pragma unroll
        for (int m2 = 0; m2 < 10; ++m2) {
            int li = i8 + 8*m2, s = s0 + li;
            bool act = (li < SPW) && (s < S_);
            int sq = (s <= S_-1) ? s : S_-1;
            s16x8 qv = *(const s16x8*)&q_l[sq*64 + (d0 ^ ((sq&7)<<3))];
            float ur = 0.f, ui = 0.f;
            #pragma unroll
            for (int j = 0; j < 8; ++j) {
                float qf = bf2f(qv[j]);
                ur = fmaf(qf, kzr[j], ur);
                ui = fmaf(qf, kzi[j], ui);
            }
            #pragma unroll
            for (int mm = 1; mm < 8; mm <<= 1) {
                ur += __shfl_xor(ur, mm, 64);
                ui += __shfl_xor(ui, mm, 64);
            }
            if (act && d0 == 0) {
                float2 z = zin[s];
                float urc = cc*ur, uic = cc*ui;
                float cr = ca*urc + sa*uic;
                float ci = ca*uic - sa*urc;
                float g = muv - (z.x*z.x + z.y*z.y);
                float dr = fmaf(g, z.x, fmaf(-om_r[m2], z.y, cr));
                float di = fmaf(g, z.y, fmaf( om_r[m2], z.x, ci));
                float2 zb = z_l[s];
                if (!second) {
                    z1_l[s] = make_float2(fmaf(DT_, dr, z.x), fmaf(DT_, di, z.y));
                    z_l[s]  = make_float2(fmaf(0.5f*DT_, dr, zb.x), fmaf(0.5f*DT_, di, zb.y));
                } else {
                    z_l[s]  = make_float2(fmaf(0.5f*DT_, dr, zb.x), fmaf(0.5f*DT_, di, zb.y));
                }
            }
        }
        __syncthreads();
    }
    for (int i = tid; i < S_; i += 512) zpg[i] = z_l[i];
}

// ---------------------------------------------------------------------------
// K3: dual flash attention, MFMA 16x16x32 bf16. (EXACT round-4 version, passed)
// ---------------------------------------------------------------------------
__global__ __launch_bounds__(512) void k_attn(
    const short* __restrict__ qh, const short* __restrict__ kh,
    const short* __restrict__ vh, const float* __restrict__ zp,
    const float* __restrict__ mix_logit, const float* __restrict__ band_logits,
    short* __restrict__ yh)
{
    __shared__ short q_l[128*64];
    __shared__ short k_l2[64*64];
    __shared__ short vT_l[64*64];
    __shared__ short P_l[8][2][1024];
    __shared__ float2 zs_l[128];
    __shared__ float2 zt_l[64];

    int blk = blockIdx.x;
    int bh = blk / 5, rc = blk - bh*5;
    int b = bh >> 4, h = bh & 15;
    int r0 = rc * 128;
    int tid = threadIdx.x, w = tid >> 6, lane = tid & 63;
    int c = lane & 15, g = lane >> 4;

    const short* qg = qh + (size_t)bh*S_*DH;
    const short* kg = kh + (size_t)bh*S_*DH;
    const short* vg = vh + (size_t)bh*S_*DH;
    const float2* zpg = (const float2*)zp + (size_t)bh*S_;

    #pragma unroll
    for (int i = 0; i < 2; ++i) {
        int cid = tid + 512*i;
        int row = cid >> 3, ch = cid & 7;
        int s = r0 + row;
        s16x8 val = {0,0,0,0,0,0,0,0};
        if (s < S_) val = *(const s16x8*)(qg + (size_t)s*DH + ch*8);
        *(s16x8*)&q_l[row*64 + ((ch*8) ^ ((row&7)<<3))] = val;
    }
    if (tid < 128) {
        float2 z = (r0 + tid < S_) ? zpg[r0 + tid] : make_float2(0.f,0.f);
        zs_l[tid] = make_float2(z.x*BETA_, z.y*BETA_);
    }
    __syncthreads();

    s16x8 qf0, qf1;
    {
        int row = w*16 + c;
        qf0 = *(const s16x8*)&q_l[row*64 + ((g*8)      ^ ((row&7)<<3))];
        qf1 = *(const s16x8*)&q_l[row*64 + ((g*8 + 32) ^ ((row&7)<<3))];
    }

    f32x4 accv[4], accr[4];
    float m_v[4], m_r[4], Z_v[4], Z_r[4];
    #pragma unroll
    for (int i = 0; i < 4; ++i) {
        accv[i] = (f32x4){0.f,0.f,0.f,0.f};
        accr[i] = (f32x4){0.f,0.f,0.f,0.f};
        m_v[i] = -1e30f; m_r[i] = -1e30f; Z_v[i] = 0.f; Z_r[i] = 0.f;
    }

    for (int tt = 0; tt < 10; ++tt) {
        int t0g = tt * 64;
        __syncthreads();
        {
            int row = tid >> 3, ch = tid & 7;
            int t = t0g + row;
            s16x8 val = {0,0,0,0,0,0,0,0};
            if (t < S_) val = *(const s16x8*)(kg + (size_t)t*DH + ch*8);
            *(s16x8*)&k_l2[row*64 + ((ch*8) ^ ((row&7)<<3))] = val;
        }
        {
            int t = tid >> 3, d0 = (tid & 7) << 3;
            s16x8 vv = {0,0,0,0,0,0,0,0};
            if (t0g + t < S_) vv = *(const s16x8*)(vg + (size_t)(t0g+t)*DH + d0);
            #pragma unroll
            for (int j = 0; j < 8; ++j)
                vT_l[(d0+j)*64 + (t ^ (((d0+j)&7)<<3))] = vv[j];
        }
        if (tid < 64) zt_l[tid] = (t0g + tid < S_) ? zpg[t0g + tid] : make_float2(0.f,0.f);
        __syncthreads();

        f32x4 sv[4];
        #pragma unroll
        for (int sub = 0; sub < 4; ++sub) {
            int row = sub*16 + c;
            s16x8 kf0 = *(const s16x8*)&k_l2[row*64 + ((g*8)      ^ ((c&7)<<3))];
            s16x8 kf1 = *(const s16x8*)&k_l2[row*64 + ((g*8 + 32) ^ ((c&7)<<3))];
            f32x4 a = {0.f,0.f,0.f,0.f};
            a = __builtin_amdgcn_mfma_f32_16x16x32_bf16(qf0, kf0, a, 0, 0, 0);
            a = __builtin_amdgcn_mfma_f32_16x16x32_bf16(qf1, kf1, a, 0, 0, 0);
            sv[sub] = a * SCALE_;
        }
        float2 zt_s[4];
        #pragma unroll
        for (int sub = 0; sub < 4; ++sub) zt_s[sub] = zt_l[sub*16 + c];

        bool mask = (t0g + 63 >= S_);
        #pragma unroll
        for (int r = 0; r < 4; ++r) {
            int srow = w*16 + (g<<2) + r;
            float2 zs = zs_l[srow];
            float sv_r[4], sr_r[4];
            #pragma unroll
            for (int sub = 0; sub < 4; ++sub) {
                float a = sv[sub][r];
                float rr = fmaf(zs.x, zt_s[sub].x, zs.y * zt_s[sub].y);
                bool bad = mask && ((t0g + sub*16 + c) >= S_);
                sv_r[sub] = bad ? -1e30f : a;
                sr_r[sub] = bad ? -1e30f : rr;
            }
            float mlv = fmaxf(fmaxf(sv_r[0],sv_r[1]), fmaxf(sv_r[2],sv_r[3]));
            float mlr = fmaxf(fmaxf(sr_r[0],sr_r[1]), fmaxf(sr_r[2],sr_r[3]));
            #pragma unroll
            for (int mm = 1; mm < 16; mm <<= 1) {
                mlv = fmaxf(mlv, __shfl_xor(mlv, mm, 64));
                mlr = fmaxf(mlr, __shfl_xor(mlr, mm, 64));
            }
            float nmv = fmaxf(m_v[r], mlv), nmr = fmaxf(m_r[r], mlr);
            float fv = __expf(m_v[r] - nmv), fr = __expf(m_r[r] - nmr);
            m_v[r] = nmv; m_r[r] = nmr;
            int sl = (g<<2) + r;
            float sumv = 0.f, sumr = 0.f;
            #pragma unroll
            for (int sub = 0; sub < 4; ++sub) {
                float pv = __expf(sv_r[sub] - nmv);
                float pr = __expf(sr_r[sub] - nmr);
                sumv += pv; sumr += pr;
                int t = sub*16 + c;
                P_l[w][0][sl*64 + (t ^ ((sl&7)<<3))] = f2bf(pv);
                P_l[w][1][sl*64 + (t ^ ((sl&7)<<3))] = f2bf(pr);
            }
            #pragma unroll
            for (int mm = 1; mm < 16; mm <<= 1) {
                sumv += __shfl_xor(sumv, mm, 64);
                sumr += __shfl_xor(sumr, mm, 64);
            }
            Z_v[r] = fmaf(Z_v[r], fv, sumv);
            Z_r[r] = fmaf(Z_r[r], fr, sumr);
            #pragma unroll
            for (int d = 0; d < 4; ++d) { accv[d][r] *= fv; accr[d][r] *= fr; }
        }

        #pragma unroll
        for (int hh = 0; hh < 2; ++hh) {
            int kc = g*8 + 32*hh;
            s16x8 pa_v = *(const s16x8*)&P_l[w][0][c*64 + (kc ^ ((c&7)<<3))];
            s16x8 pa_r = *(const s16x8*)&P_l[w][1][c*64 + (kc ^ ((c&7)<<3))];
            #pragma unroll
            for (int d = 0; d < 4; ++d) {
                int row = d*16 + c;
                s16x8 vf = *(const s16x8*)&vT_l[row*64 + (kc ^ ((c&7)<<3))];
                accv[d] = __builtin_amdgcn_mfma_f32_16x16x32_bf16(pa_v, vf, accv[d], 0, 0, 0);
                accr[d] = __builtin_amdgcn_mfma_f32_16x16x32_bf16(pa_r, vf, accr[d], 0, 0, 0);
            }
        }
    }

    float mixv = 1.f/(1.f + __expf(-mix_logit[h]));
    #pragma unroll
    for (int d = 0; d < 4; ++d) {
        float gate = 1.f/(1.f + __expf(-band_logits[h*4 + d]));
        #pragma unroll
        for (int r = 0; r < 4; ++r) {
            int s = r0 + w*16 + (g<<2) + r;
            if (s < S_) {
                float val = mixv*gate*(accr[d][r]/Z_r[r]) + (1.f-mixv)*(accv[d][r]/Z_v[r]);
                yh[(size_t)b*S_*DM + (size_t)s*DM + h*DH + d*16 + c] = f2bf(val);
            }
        }
    }
}

// ---------------------------------------------------------------------------
// K4b: Wo (f32 [k][n]) -> WoT (bf16 [n][k]) tile transpose
// ---------------------------------------------------------------------------
__global__ __launch_bounds__(256) void k_cvt(
    const float* __restrict__ Wo, short* __restrict__ Bt)
{
    __shared__ short tl[64][65];
    int k0 = blockIdx.x * 64, n0 = blockIdx.y * 64;
    int tid = threadIdx.x;
    int r = tid >> 2, cb = (tid & 3) * 16;
    #pragma unroll
    for (int j4 = 0; j4 < 4; ++j4) {
        float4 v = *reinterpret_cast<const float4*>(Wo + (size_t)(k0+r)*1024 + n0 + cb + j4*4);
        tl[r][cb + j4*4 + 0] = f2bf(v.x);
        tl[r][cb + j4*4 + 1] = f2bf(v.y);
        tl[r][cb + j4*4 + 2] = f2bf(v.z);
        tl[r][cb + j4*4 + 3] = f2bf(v.w);
    }
    __syncthreads();
    s16x8 v0, v1;
    #pragma unroll
    for (int j = 0; j < 8; ++j) { v0[j] = tl[cb+j][r]; v1[j] = tl[cb+8+j][r]; }
    *(s16x8*)(Bt + (size_t)(n0+r)*1024 + k0 + cb)     = v0;
    *(s16x8*)(Bt + (size_t)(n0+r)*1024 + k0 + cb + 8) = v1;
}

// ---------------------------------------------------------------------------
// K4: out = y(9232x1024 bf16) @ Wo + bo, MFMA 16x16x32 bf16, 128x128 tile.
// ---------------------------------------------------------------------------
__global__ __launch_bounds__(256) void k_gemm(
    const short* __restrict__ A, const short* __restrict__ Bt,
    const float* __restrict__ bias, float* __restrict__ out)
{
    const int M = B_ * S_;
    __shared__ short A_l[128*64];
    __shared__ short B_l[128*64];
    int m0 = blockIdx.x * 128, n0 = blockIdx.y * 128;
    int tid = threadIdx.x, w = tid >> 6, lane = tid & 63;
    int c = lane & 15, g = lane >> 4;
    int mb = (w & 1) * 64, nb = (w >> 1) * 64;
    f32x4 acc[4][4];
    #pragma unroll
    for (int i = 0; i < 4; ++i)
        #pragma unroll
        for (int j = 0; j < 4; ++j) acc[i][j] = (f32x4){0.f,0.f,0.f,0.f};
    for (int k0 = 0; k0 < 1024; k0 += 64) {
        __syncthreads();
        #pragma unroll
        for (int i = 0; i < 4; ++i) {
            int cid = tid + 256*i;
            int row = cid >> 3, ch = cid & 7;
            int m = m0 + row;
            s16x8 av = {0,0,0,0,0,0,0,0};
            if (m < M) av = *(const s16x8*)(A + (size_t)m*1024 + k0 + ch*8);
            *(s16x8*)&A_l[row*64 + ((ch*8) ^ ((row&7)<<3))] = av;
            s16x8 bv = *(const s16x8*)(Bt + (size_t)(n0+row)*1024 + k0 + ch*8);
            *(s16x8*)&B_l[row*64 + ((ch*8) ^ ((row&7)<<3))] = bv;
        }
        __syncthreads();
        s16x8 af[4][2], bf[4][2];
        #pragma unroll
        for (int i = 0; i < 4; ++i) {
            int ra = mb + i*16 + c;
            af[i][0] = *(const s16x8*)&A_l[ra*64 + ((g*8)      ^ ((c&7)<<3))];
            af[i][1] = *(const s16x8*)&A_l[ra*64 + ((g*8 + 32) ^ ((c&7)<<3))];
            int rb = nb + i*16 + c;
            bf[i][0] = *(const s16x8*)&B_l[rb*64 + ((g*8)      ^ ((c&7)<<3))];
            bf[i][1] = *(const s16x8*)&B_l[rb*64 + ((g*8 + 32) ^ ((c&7)<<3))];
        }
        #pragma unroll
        for (int i = 0; i < 4; ++i)
            #pragma unroll
            for (int j = 0; j < 4; ++j) {
                acc[i][j] = __builtin_amdgcn_mfma_f32_16x16x32_bf16(af[i][0], bf[j][0], acc[i][j], 0, 0, 0);
                acc[i][j] = __builtin_amdgcn_mfma_f32_16x16x32_bf16(af[i][1], bf[j][1], acc[i][j], 0, 0, 0);
            }
    }
    #pragma unroll
    for (int j = 0; j < 4; ++j) {
        float bv = bias[n0 + nb + j*16 + c];
        #pragma unroll
        for (int i = 0; i < 4; ++i)
            #pragma unroll
            for (int r = 0; r < 4; ++r) {
                int m = m0 + mb + i*16 + 4*g + r;
                if (m < M) out[(size_t)m*1024 + n0 + nb + j*16 + c] = acc[i][j][r] + bv;
            }
    }
}

// ---------------------------------------------------------------------------
extern "C" void kernel_launch(void* const* d_in, const int* in_sizes, int n_in,
                              void* d_out, int out_size, void* d_ws, size_t ws_size,
                              hipStream_t stream)
{
    const float* x   = (const float*)d_in[0];
    const float* Wq  = (const float*)d_in[1];
    const float* bq  = (const float*)d_in[2];
    const float* Wk  = (const float*)d_in[3];
    const float* bk  = (const float*)d_in[4];
    const float* Wv  = (const float*)d_in[5];
    const float* bv  = (const float*)d_in[6];
    const float* Wom = (const float*)d_in[7];
    const float* bom = (const float*)d_in[8];
    const float* Wth = (const float*)d_in[9];
    const float* bth = (const float*)d_in[10];
    const float* mu  = (const float*)d_in[11];
    const float* kap = (const float*)d_in[12];
    const float* alp = (const float*)d_in[13];
    const float* mix = (const float*)d_in[14];
    const float* bl  = (const float*)d_in[15];
    const float* Wo  = (const float*)d_in[16];
    const float* bo  = (const float*)d_in[17];
    const int* nsim  = (const int*)d_in[18];

    float* ws = (float*)d_ws;
    const size_t QKV = (size_t)BH_ * S_ * DH;    // 9,453,568
    float* qf = ws;                               // slot A (aliased below)
    float* kf = qf + QKV;                         // slot B (aliased below)
    float* om = kf + QKV;                         // BH*S
    float* zp = om + (size_t)BH_*S_;              // 2*BH*S
    short* qh = (short*)(zp + (size_t)2*BH_*S_);  // bf16 q
    short* kh = qh + QKV;                         // bf16 k
    short* vh = kh + QKV;                         // bf16 v
    short* yh  = (short*)qf;                      // bf16 y (attn out)
    short* WoT = (short*)kf;                      // bf16 Wo^T
    float* outf = (float*)d_out;

    k_proj<<<BH_, 512, 0, stream>>>(x, Wq, bq, Wk, bk, Wv, bv, Wom, bom, Wth, bth,
                                    qh, kh, vh, om, zp);
    k_ode<<<BH_, 512, 0, stream>>>(qh, kh, om, mu, kap, alp, nsim, zp);
    k_cvt<<<dim3(16,16), 256, 0, stream>>>(Wo, WoT);
    k_attn<<<BH_*5, 512, 0, stream>>>(qh, kh, vh, zp, mix, bl, yh);
    dim3 gg(73, 8);
    k_gemm<<<gg, 256, 0, stream>>>(yh, WoT, bo, outf);
}

// Round 8
// 353.234 us; speedup vs baseline: 3.0600x; 1.1810x over previous
//
#include <hip/hip_runtime.h>
#include <hip/hip_bf16.h>

#define S_ 577
#define B_ 16
#define H_ 16
#define DH 64
#define DM 1024
#define BH_ 256
#define DT_ 0.01f
#define BETA_ 4.0f
#define SCALE_ 0.125f
#define SPW 73      // s-rows per wave (k_ode phase B)
#define SPP 292     // s-pairs in k_ode phase A
#define KPR 293     // k_ode kp row stride (odd -> conflict-free)
#define OFFV 4.0f   // static exp offset, vanilla (|sv| <= 3.3 hard bound)
#define OFFR 6.0f   // static exp offset, resonance (|sr| <= ~5.3 hard bound)

typedef float f32x4 __attribute__((ext_vector_type(4)));
typedef short s16x8 __attribute__((ext_vector_type(8)));

__device__ inline short f2bf(float x) {
    unsigned b = __builtin_bit_cast(unsigned, x);
    b += 0x7fffu + ((b >> 16) & 1u);
    return (short)(b >> 16);
}
__device__ inline float bf2f(short s) {
    unsigned u = ((unsigned)(unsigned short)s) << 16;
    return __builtin_bit_cast(float, u);
}
// bank-spreading swizzles (write & read MUST use the same formula of row)
__device__ inline int vswz(int row) { return (((row >> 3) ^ row) & 7) << 3; }
__device__ inline int pswz(int row) { return ((row ^ (row >> 1)) & 7) << 3; }

// ---------------------------------------------------------------------------
// K1: per-(b,h) projections via MFMA. (unchanged, validated r7)
// ---------------------------------------------------------------------------
__global__ __launch_bounds__(512) void k_proj(
    const float* __restrict__ x,
    const float* __restrict__ Wq, const float* __restrict__ bq,
    const float* __restrict__ Wk, const float* __restrict__ bk,
    const float* __restrict__ Wv, const float* __restrict__ bv,
    const float* __restrict__ Wom, const float* __restrict__ bom,
    const float* __restrict__ Wth, const float* __restrict__ bth,
    short* __restrict__ qh, short* __restrict__ kh, short* __restrict__ vh,
    float* __restrict__ om, float* __restrict__ zp)
{
    __shared__ __align__(16) short WqT[64*64], WkT[64*64], WvT[64*64];
    __shared__ __align__(16) short X_l[128*64];
    __shared__ float Wom_l[64], Wth_l[64];

    int bh = blockIdx.x, b = bh >> 4, h = bh & 15;
    int tid = threadIdx.x, w = tid >> 6, lane = tid & 63;
    int c = lane & 15, g = lane >> 4;

    {
        int d = tid >> 3, e0 = (tid & 7) << 3;
        const float* pq = Wq + (size_t)h*4096 + d*64 + e0;
        const float* pk = Wk + (size_t)h*4096 + d*64 + e0;
        const float* pv = Wv + (size_t)h*4096 + d*64 + e0;
        float4 q0 = *(const float4*)pq, q1 = *(const float4*)(pq + 4);
        float4 k0 = *(const float4*)pk, k1 = *(const float4*)(pk + 4);
        float4 v0 = *(const float4*)pv, v1 = *(const float4*)(pv + 4);
        float qv[8] = {q0.x,q0.y,q0.z,q0.w,q1.x,q1.y,q1.z,q1.w};
        float kv[8] = {k0.x,k0.y,k0.z,k0.w,k1.x,k1.y,k1.z,k1.w};
        float vv[8] = {v0.x,v0.y,v0.z,v0.w,v1.x,v1.y,v1.z,v1.w};
        #pragma unroll
        for (int j = 0; j < 8; ++j) {
            int e = e0 + j;
            int off = e*64 + (d ^ ((e&7)<<3));
            WqT[off] = f2bf(qv[j]);
            WkT[off] = f2bf(kv[j]);
            WvT[off] = f2bf(vv[j]);
        }
    }
    if (tid < 64) { Wom_l[tid] = Wom[h*64 + tid]; Wth_l[tid] = Wth[h*64 + tid]; }

    float bqv[4], bkv[4], bvv[4];
    #pragma unroll
    for (int e4 = 0; e4 < 4; ++e4) {
        bqv[e4] = bq[h*64 + e4*16 + c];
        bkv[e4] = bk[h*64 + e4*16 + c];
        bvv[e4] = bv[h*64 + e4*16 + c];
    }
    float bomv = bom[h], bthv = bth[h];

    const size_t xbase = (size_t)b*S_*DM + (size_t)h*DH;

    for (int t5 = 0; t5 < 5; ++t5) {
        int s0 = t5 * 128;
        __syncthreads();
        #pragma unroll
        for (int i = 0; i < 2; ++i) {
            int cid = tid + 512*i;
            int row = cid >> 3, ch = cid & 7;
            int s = s0 + row;
            float xv[8];
            if (s < S_) {
                const float* px = x + xbase + (size_t)s*DM + ch*8;
                float4 a0 = *(const float4*)px, a1 = *(const float4*)(px + 4);
                xv[0]=a0.x; xv[1]=a0.y; xv[2]=a0.z; xv[3]=a0.w;
                xv[4]=a1.x; xv[5]=a1.y; xv[6]=a1.z; xv[7]=a1.w;
                #pragma unroll
                for (int j = 0; j < 8; ++j) if (!isfinite(xv[j])) xv[j] = 0.f;
            } else {
                #pragma unroll
                for (int j = 0; j < 8; ++j) xv[j] = 0.f;
            }
            s16x8 xb;
            #pragma unroll
            for (int j = 0; j < 8; ++j) xb[j] = f2bf(xv[j]);
            *(s16x8*)&X_l[row*64 + ((ch*8) ^ ((row&7)<<3))] = xb;
            float po = 0.f, pt = 0.f;
            #pragma unroll
            for (int j = 0; j < 8; ++j) {
                po = fmaf(xv[j], Wom_l[ch*8 + j], po);
                pt = fmaf(xv[j], Wth_l[ch*8 + j], pt);
            }
            po += __shfl_xor(po, 1, 64); pt += __shfl_xor(pt, 1, 64);
            po += __shfl_xor(po, 2, 64); pt += __shfl_xor(pt, 2, 64);
            po += __shfl_xor(po, 4, 64); pt += __shfl_xor(pt, 4, 64);
            if (ch == 0 && s < S_) {
                om[(size_t)bh*S_ + s] = po + bomv;
                float si, co;
                sincosf(pt + bthv, &si, &co);
                reinterpret_cast<float2*>(zp)[(size_t)bh*S_ + s] = make_float2(co, si);
            }
        }
        __syncthreads();
        int arow = w*16 + c;
        s16x8 xa0 = *(const s16x8*)&X_l[arow*64 + ((g*8)      ^ ((arow&7)<<3))];
        s16x8 xa1 = *(const s16x8*)&X_l[arow*64 + ((g*8 + 32) ^ ((arow&7)<<3))];

        const short* WT[3] = {WqT, WkT, WvT};
        short* dst[3] = {qh, kh, vh};
        #pragma unroll
        for (int o = 0; o < 3; ++o) {
            f32x4 acc[4];
            #pragma unroll
            for (int e4 = 0; e4 < 4; ++e4) {
                int brow = e4*16 + c;
                s16x8 b0 = *(const s16x8*)&WT[o][brow*64 + ((g*8)      ^ ((brow&7)<<3))];
                s16x8 b1 = *(const s16x8*)&WT[o][brow*64 + ((g*8 + 32) ^ ((brow&7)<<3))];
                f32x4 a = {0.f,0.f,0.f,0.f};
                a = __builtin_amdgcn_mfma_f32_16x16x32_bf16(xa0, b0, a, 0, 0, 0);
                a = __builtin_amdgcn_mfma_f32_16x16x32_bf16(xa1, b1, a, 0, 0, 0);
                acc[e4] = a;
            }
            float* bias = (o == 0) ? bqv : (o == 1) ? bkv : bvv;
            #pragma unroll
            for (int e4 = 0; e4 < 4; ++e4) {
                #pragma unroll
                for (int r = 0; r < 4; ++r) {
                    int s = s0 + w*16 + 4*g + r;
                    if (s < S_)
                        dst[o][(size_t)bh*S_*DH + (size_t)s*DH + e4*16 + c] =
                            f2bf(acc[e4][r] + bias[e4]);
                }
            }
        }
    }
}

// ---------------------------------------------------------------------------
// K2: Stuart-Landau ODE, LDS-resident bf16 k/q. (unchanged, validated r4)
// ---------------------------------------------------------------------------
__global__ __launch_bounds__(512) void k_ode(
    const short* __restrict__ qh, const short* __restrict__ kh,
    const float* __restrict__ om,
    const float* __restrict__ mu, const float* __restrict__ kappa,
    const float* __restrict__ alpha, const int* __restrict__ nsim,
    float* __restrict__ zp)
{
    __shared__ __align__(16) unsigned kp_l[64*KPR];
    __shared__ __align__(16) short    q_l[S_*64];
    __shared__ __align__(16) float2   z_l[584];
    __shared__ __align__(16) float2   z1_l[584];
    __shared__ __align__(16) float2   kz_s[8][64];

    int bh = blockIdx.x, h = bh & 15;
    int tid = threadIdx.x, w = tid >> 6, lane = tid & 63;
    const short* kg = kh + (size_t)bh*S_*DH;
    const short* qg = qh + (size_t)bh*S_*DH;
    float2* zpg = reinterpret_cast<float2*>(zp) + (size_t)bh*S_;
    const float* omg = om + (size_t)bh*S_;

    for (int i = tid; i < 584; i += 512) {
        z_l[i] = (i < S_) ? zpg[i] : make_float2(0.f, 0.f);
        z1_l[i] = make_float2(0.f, 0.f);
    }
    {
        int e0 = (tid & 7) * 8;
        for (int sp = tid >> 3; sp < SPP; sp += 64) {
            int sA = 2*sp, sB = 2*sp + 1;
            s16x8 ka = {0,0,0,0,0,0,0,0}, kb = ka;
            if (sA < S_) ka = *(const s16x8*)(kg + (size_t)sA*DH + e0);
            if (sB < S_) kb = *(const s16x8*)(kg + (size_t)sB*DH + e0);
            #pragma unroll
            for (int j = 0; j < 8; ++j)
                kp_l[(e0+j)*KPR + sp] =
                    ((unsigned)(unsigned short)ka[j]) |
                    (((unsigned)(unsigned short)kb[j]) << 16);
        }
    }
    for (int cid = tid; cid < S_*8; cid += 512) {
        int s = cid >> 3, c = cid & 7;
        s16x8 v = *(const s16x8*)(qg + (size_t)s*DH + c*8);
        *(s16x8*)&q_l[s*64 + ((c*8) ^ ((s&7)<<3))] = v;
    }
    int i8 = lane >> 3, d0 = (lane & 7) << 3;
    int s0 = w * SPW;
    float om_r[10];
    #pragma unroll
    for (int m2 = 0; m2 < 10; ++m2) {
        int li = i8 + 8*m2, s = s0 + li;
        om_r[m2] = (li < SPW && s < S_) ? omg[s] : 0.f;
    }
    float ca = cosf(alpha[h]), sa = sinf(alpha[h]);
    float muv = mu[h];
    float cc = kappa[h] * SCALE_ / (float)S_;
    int NT = nsim[0];
    int sp0 = w * 37, spE = min(SPP, sp0 + 37);
    __syncthreads();

    for (int ev = 0; ev < 2*NT; ++ev) {
        bool second = ev & 1;
        const float2* zin = second ? z1_l : z_l;
        float ar = 0.f, ai = 0.f, br = 0.f, bi = 0.f;
        for (int sp = sp0; sp < spE; ++sp) {
            unsigned kv = kp_l[lane*KPR + sp];
            float4 zz = *reinterpret_cast<const float4*>(&zin[2*sp]);
            float klo = __builtin_bit_cast(float, kv << 16);
            float khi = __builtin_bit_cast(float, kv & 0xffff0000u);
            ar = fmaf(klo, zz.x, ar); ai = fmaf(klo, zz.y, ai);
            br = fmaf(khi, zz.z, br); bi = fmaf(khi, zz.w, bi);
        }
        kz_s[w][lane] = make_float2(ar + br, ai + bi);
        __syncthreads();
        float sr = 0.f, si = 0.f;
        #pragma unroll
        for (int w2 = 0; w2 < 8; ++w2) {
            float2 t = kz_s[w2][lane];
            sr += t.x; si += t.y;
        }
        float kzr[8], kzi[8];
        #pragma unroll
        for (int j = 0; j < 8; ++j) {
            kzr[j] = __shfl(sr, d0 + j, 64);
            kzi[j] = __shfl(si, d0 + j, 64);
        }
        #pragma unroll
        for (int m2 = 0; m2 < 10; ++m2) {
            int li = i8 + 8*m2, s = s0 + li;
            bool act = (li < SPW) && (s < S_);
            int sq = (s <= S_-1) ? s : S_-1;
            s16x8 qv = *(const s16x8*)&q_l[sq*64 + (d0 ^ ((sq&7)<<3))];
            float ur = 0.f, ui = 0.f;
            #pragma unroll
            for (int j = 0; j < 8; ++j) {
                float qf = bf2f(qv[j]);
                ur = fmaf(qf, kzr[j], ur);
                ui = fmaf(qf, kzi[j], ui);
            }
            #pragma unroll
            for (int mm = 1; mm < 8; mm <<= 1) {
                ur += __shfl_xor(ur, mm, 64);
                ui += __shfl_xor(ui, mm, 64);
            }
            if (act && d0 == 0) {
                float2 z = zin[s];
                float urc = cc*ur, uic = cc*ui;
                float cr = ca*urc + sa*uic;
                float ci = ca*uic - sa*urc;
                float g = muv - (z.x*z.x + z.y*z.y);
                float dr = fmaf(g, z.x, fmaf(-om_r[m2], z.y, cr));
                float di = fmaf(g, z.y, fmaf( om_r[m2], z.x, ci));
                float2 zb = z_l[s];
                if (!second) {
                    z1_l[s] = make_float2(fmaf(DT_, dr, z.x), fmaf(DT_, di, z.y));
                    z_l[s]  = make_float2(fmaf(0.5f*DT_, dr, zb.x), fmaf(0.5f*DT_, di, zb.y));
                } else {
                    z_l[s]  = make_float2(fmaf(0.5f*DT_, dr, zb.x), fmaf(0.5f*DT_, di, zb.y));
                }
            }
        }
        __syncthreads();
    }
    for (int i = tid; i < S_; i += 512) zpg[i] = z_l[i];
}

// ---------------------------------------------------------------------------
// K3: dual flash attention, MFMA 16x16x32 bf16. r4 dataflow with:
// (a) no-max softmax: P = exp(score - OFF), statically-bounded scores; Z
//     accumulated lane-locally, reduced once at the end (0 per-tile shfl);
// (b) vT swizzle vswz(row) — conflict-free scatter write AND b128 read;
// (c) P swizzle pswz(row) — conflict-free scalar write AND b128 read.
// ---------------------------------------------------------------------------
__global__ __launch_bounds__(512) void k_attn(
    const short* __restrict__ qh, const short* __restrict__ kh,
    const short* __restrict__ vh, const float* __restrict__ zp,
    const float* __restrict__ mix_logit, const float* __restrict__ band_logits,
    short* __restrict__ yh)
{
    __shared__ short q_l[128*64];
    __shared__ short k_l2[64*64];
    __shared__ short vT_l[64*64];
    __shared__ short P_l[8][2][1024];
    __shared__ float2 zs_l[128];
    __shared__ float2 zt_l[64];

    int blk = blockIdx.x;
    int bh = blk / 5, rc = blk - bh*5;
    int b = bh >> 4, h = bh & 15;
    int r0 = rc * 128;
    int tid = threadIdx.x, w = tid >> 6, lane = tid & 63;
    int c = lane & 15, g = lane >> 4;

    const short* qg = qh + (size_t)bh*S_*DH;
    const short* kg = kh + (size_t)bh*S_*DH;
    const short* vg = vh + (size_t)bh*S_*DH;
    const float2* zpg = (const float2*)zp + (size_t)bh*S_;

    #pragma unroll
    for (int i = 0; i < 2; ++i) {
        int cid = tid + 512*i;
        int row = cid >> 3, ch = cid & 7;
        int s = r0 + row;
        s16x8 val = {0,0,0,0,0,0,0,0};
        if (s < S_) val = *(const s16x8*)(qg + (size_t)s*DH + ch*8);
        *(s16x8*)&q_l[row*64 + ((ch*8) ^ ((row&7)<<3))] = val;
    }
    if (tid < 128) {
        float2 z = (r0 + tid < S_) ? zpg[r0 + tid] : make_float2(0.f,0.f);
        zs_l[tid] = make_float2(z.x*BETA_, z.y*BETA_);
    }
    __syncthreads();

    s16x8 qf0, qf1;
    {
        int row = w*16 + c;
        qf0 = *(const s16x8*)&q_l[row*64 + ((g*8)      ^ ((row&7)<<3))];
        qf1 = *(const s16x8*)&q_l[row*64 + ((g*8 + 32) ^ ((row&7)<<3))];
    }

    f32x4 accv[4], accr[4];
    float Z_v[4], Z_r[4];    // lane-local partial denominators
    #pragma unroll
    for (int i = 0; i < 4; ++i) {
        accv[i] = (f32x4){0.f,0.f,0.f,0.f};
        accr[i] = (f32x4){0.f,0.f,0.f,0.f};
        Z_v[i] = 0.f; Z_r[i] = 0.f;
    }

    for (int tt = 0; tt < 10; ++tt) {
        int t0g = tt * 64;
        __syncthreads();
        {   // stage k tile (unchanged pattern)
            int row = tid >> 3, ch = tid & 7;
            int t = t0g + row;
            s16x8 val = {0,0,0,0,0,0,0,0};
            if (t < S_) val = *(const s16x8*)(kg + (size_t)t*DH + ch*8);
            *(s16x8*)&k_l2[row*64 + ((ch*8) ^ ((row&7)<<3))] = val;
        }
        {   // stage v transposed with bank-spreading vswz
            int t = tid >> 3, d0 = (tid & 7) << 3;
            s16x8 vv = {0,0,0,0,0,0,0,0};
            if (t0g + t < S_) vv = *(const s16x8*)(vg + (size_t)(t0g+t)*DH + d0);
            #pragma unroll
            for (int j = 0; j < 8; ++j) {
                int dd = d0 + j;
                vT_l[dd*64 + (t ^ vswz(dd))] = vv[j];
            }
        }
        if (tid < 64) zt_l[tid] = (t0g + tid < S_) ? zpg[t0g + tid] : make_float2(0.f,0.f);
        __syncthreads();

        // ---- QK^T with folded scale and static offset
        f32x4 sv[4];
        #pragma unroll
        for (int sub = 0; sub < 4; ++sub) {
            int row = sub*16 + c;
            s16x8 kf0 = *(const s16x8*)&k_l2[row*64 + ((g*8)      ^ ((c&7)<<3))];
            s16x8 kf1 = *(const s16x8*)&k_l2[row*64 + ((g*8 + 32) ^ ((c&7)<<3))];
            f32x4 a = {0.f,0.f,0.f,0.f};
            a = __builtin_amdgcn_mfma_f32_16x16x32_bf16(qf0, kf0, a, 0, 0, 0);
            a = __builtin_amdgcn_mfma_f32_16x16x32_bf16(qf1, kf1, a, 0, 0, 0);
            sv[sub] = a * SCALE_ - OFFV;
        }
        float2 zt_s[4];
        #pragma unroll
        for (int sub = 0; sub < 4; ++sub) zt_s[sub] = zt_l[sub*16 + c];

        bool mask = (t0g + 63 >= S_);
        // ---- no-max softmax numerators + lane-local Z accumulation
        #pragma unroll
        for (int r = 0; r < 4; ++r) {
            int srow = w*16 + (g<<2) + r;
            float2 zs = zs_l[srow];
            int sl = (g<<2) + r;
            int psw = pswz(sl);
            float sumv = 0.f, sumr = 0.f;
            #pragma unroll
            for (int sub = 0; sub < 4; ++sub) {
                float a = sv[sub][r];
                float rr = fmaf(zs.x, zt_s[sub].x, zs.y * zt_s[sub].y) - OFFR;
                bool bad = mask && ((t0g + sub*16 + c) >= S_);
                float pv = bad ? 0.f : __expf(a);
                float pr = bad ? 0.f : __expf(rr);
                sumv += pv; sumr += pr;
                int t = sub*16 + c;
                P_l[w][0][sl*64 + (t ^ psw)] = f2bf(pv);
                P_l[w][1][sl*64 + (t ^ psw)] = f2bf(pr);
            }
            Z_v[r] += sumv;
            Z_r[r] += sumr;
        }

        // ---- PV (reads use matching swizzles)
        #pragma unroll
        for (int hh = 0; hh < 2; ++hh) {
            int kc = g*8 + 32*hh;
            int psw_c = pswz(c);
            s16x8 pa_v = *(const s16x8*)&P_l[w][0][c*64 + (kc ^ psw_c)];
            s16x8 pa_r = *(const s16x8*)&P_l[w][1][c*64 + (kc ^ psw_c)];
            #pragma unroll
            for (int d = 0; d < 4; ++d) {
                int row = d*16 + c;
                s16x8 vf = *(const s16x8*)&vT_l[row*64 + (kc ^ vswz(row))];
                accv[d] = __builtin_amdgcn_mfma_f32_16x16x32_bf16(pa_v, vf, accv[d], 0, 0, 0);
                accr[d] = __builtin_amdgcn_mfma_f32_16x16x32_bf16(pa_r, vf, accr[d], 0, 0, 0);
            }
        }
    }

    // ---- single final Z reduce over the 16-lane c-group
    #pragma unroll
    for (int mm = 1; mm < 16; mm <<= 1) {
        #pragma unroll
        for (int r = 0; r < 4; ++r) {
            Z_v[r] += __shfl_xor(Z_v[r], mm, 64);
            Z_r[r] += __shfl_xor(Z_r[r], mm, 64);
        }
    }

    float mixv = 1.f/(1.f + __expf(-mix_logit[h]));
    #pragma unroll
    for (int d = 0; d < 4; ++d) {
        float gate = 1.f/(1.f + __expf(-band_logits[h*4 + d]));
        #pragma unroll
        for (int r = 0; r < 4; ++r) {
            int s = r0 + w*16 + (g<<2) + r;
            if (s < S_) {
                float val = mixv*gate*(accr[d][r]/Z_r[r]) + (1.f-mixv)*(accv[d][r]/Z_v[r]);
                yh[(size_t)b*S_*DM + (size_t)s*DM + h*DH + d*16 + c] = f2bf(val);
            }
        }
    }
}

// ---------------------------------------------------------------------------
// K4b: Wo (f32 [k][n]) -> WoT (bf16 [n][k]) tile transpose
// ---------------------------------------------------------------------------
__global__ __launch_bounds__(256) void k_cvt(
    const float* __restrict__ Wo, short* __restrict__ Bt)
{
    __shared__ short tl[64][65];
    int k0 = blockIdx.x * 64, n0 = blockIdx.y * 64;
    int tid = threadIdx.x;
    int r = tid >> 2, cb = (tid & 3) * 16;
    #pragma unroll
    for (int j4 = 0; j4 < 4; ++j4) {
        float4 v = *reinterpret_cast<const float4*>(Wo + (size_t)(k0+r)*1024 + n0 + cb + j4*4);
        tl[r][cb + j4*4 + 0] = f2bf(v.x);
        tl[r][cb + j4*4 + 1] = f2bf(v.y);
        tl[r][cb + j4*4 + 2] = f2bf(v.z);
        tl[r][cb + j4*4 + 3] = f2bf(v.w);
    }
    __syncthreads();
    s16x8 v0, v1;
    #pragma unroll
    for (int j = 0; j < 8; ++j) { v0[j] = tl[cb+j][r]; v1[j] = tl[cb+8+j][r]; }
    *(s16x8*)(Bt + (size_t)(n0+r)*1024 + k0 + cb)     = v0;
    *(s16x8*)(Bt + (size_t)(n0+r)*1024 + k0 + cb + 8) = v1;
}

// ---------------------------------------------------------------------------
// K4: out = y(9232x1024 bf16) @ Wo + bo, MFMA 16x16x32 bf16, 128x128 tile.
// ---------------------------------------------------------------------------
__global__ __launch_bounds__(256) void k_gemm(
    const short* __restrict__ A, const short* __restrict__ Bt,
    const float* __restrict__ bias, float* __restrict__ out)
{
    const int M = B_ * S_;
    __shared__ short A_l[128*64];
    __shared__ short B_l[128*64];
    int m0 = blockIdx.x * 128, n0 = blockIdx.y * 128;
    int tid = threadIdx.x, w = tid >> 6, lane = tid & 63;
    int c = lane & 15, g = lane >> 4;
    int mb = (w & 1) * 64, nb = (w >> 1) * 64;
    f32x4 acc[4][4];
    #pragma unroll
    for (int i = 0; i < 4; ++i)
        #pragma unroll
        for (int j = 0; j < 4; ++j) acc[i][j] = (f32x4){0.f,0.f,0.f,0.f};
    for (int k0 = 0; k0 < 1024; k0 += 64) {
        __syncthreads();
        #pragma unroll
        for (int i = 0; i < 4; ++i) {
            int cid = tid + 256*i;
            int row = cid >> 3, ch = cid & 7;
            int m = m0 + row;
            s16x8 av = {0,0,0,0,0,0,0,0};
            if (m < M) av = *(const s16x8*)(A + (size_t)m*1024 + k0 + ch*8);
            *(s16x8*)&A_l[row*64 + ((ch*8) ^ ((row&7)<<3))] = av;
            s16x8 bv = *(const s16x8*)(Bt + (size_t)(n0+row)*1024 + k0 + ch*8);
            *(s16x8*)&B_l[row*64 + ((ch*8) ^ ((row&7)<<3))] = bv;
        }
        __syncthreads();
        s16x8 af[4][2], bf[4][2];
        #pragma unroll
        for (int i = 0; i < 4; ++i) {
            int ra = mb + i*16 + c;
            af[i][0] = *(const s16x8*)&A_l[ra*64 + ((g*8)      ^ ((c&7)<<3))];
            af[i][1] = *(const s16x8*)&A_l[ra*64 + ((g*8 + 32) ^ ((c&7)<<3))];
            int rb = nb + i*16 + c;
            bf[i][0] = *(const s16x8*)&B_l[rb*64 + ((g*8)      ^ ((c&7)<<3))];
            bf[i][1] = *(const s16x8*)&B_l[rb*64 + ((g*8 + 32) ^ ((c&7)<<3))];
        }
        #pragma unroll
        for (int i = 0; i < 4; ++i)
            #pragma unroll
            for (int j = 0; j < 4; ++j) {
                acc[i][j] = __builtin_amdgcn_mfma_f32_16x16x32_bf16(af[i][0], bf[j][0], acc[i][j], 0, 0, 0);
                acc[i][j] = __builtin_amdgcn_mfma_f32_16x16x32_bf16(af[i][1], bf[j][1], acc[i][j], 0, 0, 0);
            }
    }
    #pragma unroll
    for (int j = 0; j < 4; ++j) {
        float bv = bias[n0 + nb + j*16 + c];
        #pragma unroll
        for (int i = 0; i < 4; ++i)
            #pragma unroll
            for (int r = 0; r < 4; ++r) {
                int m = m0 + mb + i*16 + 4*g + r;
                if (m < M) out[(size_t)m*1024 + n0 + nb + j*16 + c] = acc[i][j][r] + bv;
            }
    }
}

// ---------------------------------------------------------------------------
extern "C" void kernel_launch(void* const* d_in, const int* in_sizes, int n_in,
                              void* d_out, int out_size, void* d_ws, size_t ws_size,
                              hipStream_t stream)
{
    const float* x   = (const float*)d_in[0];
    const float* Wq  = (const float*)d_in[1];
    const float* bq  = (const float*)d_in[2];
    const float* Wk  = (const float*)d_in[3];
    const float* bk  = (const float*)d_in[4];
    const float* Wv  = (const float*)d_in[5];
    const float* bv  = (const float*)d_in[6];
    const float* Wom = (const float*)d_in[7];
    const float* bom = (const float*)d_in[8];
    const float* Wth = (const float*)d_in[9];
    const float* bth = (const float*)d_in[10];
    const float* mu  = (const float*)d_in[11];
    const float* kap = (const float*)d_in[12];
    const float* alp = (const float*)d_in[13];
    const float* mix = (const float*)d_in[14];
    const float* bl  = (const float*)d_in[15];
    const float* Wo  = (const float*)d_in[16];
    const float* bo  = (const float*)d_in[17];
    const int* nsim  = (const int*)d_in[18];

    float* ws = (float*)d_ws;
    const size_t QKV = (size_t)BH_ * S_ * DH;    // 9,453,568
    float* qf = ws;                               // slot A (aliased below)
    float* kf = qf + QKV;                         // slot B (aliased below)
    float* om = kf + QKV;                         // BH*S
    float* zp = om + (size_t)BH_*S_;              // 2*BH*S
    short* qh = (short*)(zp + (size_t)2*BH_*S_);  // bf16 q
    short* kh = qh + QKV;                         // bf16 k
    short* vh = kh + QKV;                         // bf16 v
    short* yh  = (short*)qf;                      // bf16 y (attn out)
    short* WoT = (short*)kf;                      // bf16 Wo^T
    float* outf = (float*)d_out;

    k_proj<<<BH_, 512, 0, stream>>>(x, Wq, bq, Wk, bk, Wv, bv, Wom, bom, Wth, bth,
                                    qh, kh, vh, om, zp);
    k_ode<<<BH_, 512, 0, stream>>>(qh, kh, om, mu, kap, alp, nsim, zp);
    k_cvt<<<dim3(16,16), 256, 0, stream>>>(Wo, WoT);
    k_attn<<<BH_*5, 512, 0, stream>>>(qh, kh, vh, zp, mix, bl, yh);
    dim3 gg(73, 8);
    k_gemm<<<gg, 256, 0, stream>>>(yh, WoT, bo, outf);
}